// Round 8
// baseline (395.546 us; speedup 1.0000x reference)
//
#include <hip/hip_runtime.h>
#include <hip/hip_bf16.h>
#include <math.h>

#define NN 20000
#define DD 128
#define CC1 256
#define CC2 32
#define X1_SPLIT 128

__device__ __forceinline__ unsigned short f2bf(float f) {
    unsigned int b = __float_as_uint(f);
    b = (b + 0x7fffu + ((b >> 16) & 1u)) >> 16;
    return (unsigned short)b;
}
__device__ __forceinline__ float bfu(unsigned short u) { return __uint_as_float((unsigned int)u << 16); }
__device__ __forceinline__ float bf_lo(unsigned int u) { return __uint_as_float(u << 16); }
__device__ __forceinline__ float bf_hi(unsigned int u) { return __uint_as_float(u & 0xffff0000u); }

// ---------------- CSR build ----------------
__global__ void k_count(const int* __restrict__ dst, int* __restrict__ cnt, int E) {
    int e = blockIdx.x * blockDim.x + threadIdx.x;
    if (e < E) atomicAdd(&cnt[dst[e]], 1);
}

__global__ void k_scan(const int* __restrict__ cnt, int* __restrict__ offs, int n) {
    __shared__ int part[1024];
    int t = threadIdx.x;
    int chunk = (n + 1023) / 1024;
    int lo = t * chunk, hi = min(lo + chunk, n);
    int s = 0;
    for (int i = lo; i < hi; i++) s += cnt[i];
    part[t] = s;
    __syncthreads();
    for (int d = 1; d < 1024; d <<= 1) {
        int v = (t >= d) ? part[t - d] : 0;
        __syncthreads();
        part[t] += v;
        __syncthreads();
    }
    int base = (t > 0) ? part[t - 1] : 0;
    for (int i = lo; i < hi; i++) { offs[i] = base; base += cnt[i]; }
    if (t == 1023) offs[n] = part[1023];
}

__global__ void k_fill(const int* __restrict__ src, const int* __restrict__ dst,
                       const int* __restrict__ offs, int* __restrict__ fill,
                       int* __restrict__ csr_src, int E) {
    int e = blockIdx.x * blockDim.x + threadIdx.x;
    if (e < E) {
        int d = dst[e];
        int pos = atomicAdd(&fill[d], 1);
        csr_src[offs[d] + pos] = src[e];
    }
}

// ---------------- bf16 pre-conversion of feature + Wa1, fused attW1-fold (last block) ----------------
__global__ __launch_bounds__(256) void k_prepfold(const float* __restrict__ feature,
                                                  const float* __restrict__ Wa1,
                                                  const float* __restrict__ ba1,
                                                  const float* __restrict__ attW1,
                                                  const float* __restrict__ attb1,
                                                  unsigned short* __restrict__ feat_bf,
                                                  unsigned short* __restrict__ Wa1b,
                                                  float* __restrict__ fold,
                                                  int nf4, int prepBlocks) {
    if ((int)blockIdx.x == prepBlocks) {
        int t = threadIdx.x;
        if (t < 128) {
            float vs = 0.f, vd = 0.f;
            for (int k = 0; k < CC1; k++) {
                float w = Wa1[t * CC1 + k];
                vs += w * attW1[k];
                vd += w * attW1[CC1 + k];
            }
            fold[t] = vs;
            fold[128 + t] = vd;
            if (t == 0) {
                float c = attb1[0];
                for (int k = 0; k < CC1; k++) c += ba1[k] * (attW1[k] + attW1[CC1 + k]);
                fold[256] = c;
            }
        }
        return;
    }
    int i = blockIdx.x * 256 + threadIdx.x;
    int tot = nf4 + 128 * 256 / 4;
    if (i >= tot) return;
    float4 v;
    if (i < nf4) v = ((const float4*)feature)[i];
    else         v = ((const float4*)Wa1)[i - nf4];
    ushort4 u;
    u.x = f2bf(v.x); u.y = f2bf(v.y); u.z = f2bf(v.z); u.w = f2bf(v.w);
    if (i < nf4) ((ushort4*)feat_bf)[i] = u;
    else         ((ushort4*)Wa1b)[i - nf4] = u;
}

// ---------------- fused gather-mean + row GEMM [32x128]x[128x128] per block ----------------
// Gathers bf16 rows per CSR, means into swizzled sT, then GEMM from LDS.
// MODE 0: L2-normalize rows -> out f32 + out_bf
// MODE 1: out_bf only (z1 bf16); a_src/a_dst via folded attention vectors
template <int MODE>
__global__ __launch_bounds__(256) void k_mgemm(const unsigned short* __restrict__ src_bf,
                                               const int* __restrict__ offs,
                                               const int* __restrict__ csr,
                                               const float* __restrict__ W,
                                               const float* __restrict__ b,
                                               float* __restrict__ out,
                                               unsigned short* __restrict__ out_bf,
                                               const float* __restrict__ fold,
                                               float* __restrict__ a_src,
                                               float* __restrict__ a_dst, int n) {
    __shared__ float sW[128 * 128];   // 64 KB
    __shared__ float sT[128 * 32];    // 16 KB, swizzled transposed mean rows
    int t = threadIdx.x;
    for (int i = t; i < 4096; i += 256) ((float4*)sW)[i] = ((const float4*)W)[i];
    int r0 = blockIdx.x * 32;
    int wv = t >> 6, lane = t & 63, half = lane >> 5, l32 = lane & 31;
    const ushort4* f = (const ushort4*)src_bf;
    // each wave gathers+means 8 rows: rows wv*8 .. wv*8+7
    for (int nd = 0; nd < 8; nd++) {
        int row = wv * 8 + nd;
        int node = r0 + row;
        int lo = offs[node], hi = offs[node + 1];
        float4 acc = make_float4(0.f, 0.f, 0.f, 0.f);
        int i = lo + half;
        while (i + 6 < hi) {
            int s0 = csr[i], s1v = csr[i + 2], s2 = csr[i + 4], s3 = csr[i + 6];
            ushort4 v0 = f[(size_t)s0 * 32 + l32];
            ushort4 v1 = f[(size_t)s1v * 32 + l32];
            ushort4 v2 = f[(size_t)s2 * 32 + l32];
            ushort4 v3 = f[(size_t)s3 * 32 + l32];
            acc.x += bfu(v0.x) + bfu(v1.x) + bfu(v2.x) + bfu(v3.x);
            acc.y += bfu(v0.y) + bfu(v1.y) + bfu(v2.y) + bfu(v3.y);
            acc.z += bfu(v0.z) + bfu(v1.z) + bfu(v2.z) + bfu(v3.z);
            acc.w += bfu(v0.w) + bfu(v1.w) + bfu(v2.w) + bfu(v3.w);
            i += 8;
        }
        while (i < hi) {
            ushort4 v = f[(size_t)csr[i] * 32 + l32];
            acc.x += bfu(v.x); acc.y += bfu(v.y); acc.z += bfu(v.z); acc.w += bfu(v.w);
            i += 2;
        }
        acc.x += __shfl_xor(acc.x, 32);
        acc.y += __shfl_xor(acc.y, 32);
        acc.z += __shfl_xor(acc.z, 32);
        acc.w += __shfl_xor(acc.w, 32);
        if (half == 0) {
            float inv = 1.0f / (float)max(hi - lo, 1);
            int k0 = l32 * 4;  // channels k0..k0+3; k>>4 == l32>>2 for all 4
            int base = (((row >> 2) ^ (l32 >> 2)) << 2) + (row & 3);
            sT[(k0 + 0) * 32 + base] = acc.x * inv;
            sT[(k0 + 1) * 32 + base] = acc.y * inv;
            sT[(k0 + 2) * 32 + base] = acc.z * inv;
            sT[(k0 + 3) * 32 + base] = acc.w * inv;
        }
    }
    int j4 = (lane & 31) * 4;
    int rg = wv * 2 + (lane >> 5);    // 0..7 -> rows rg*4..rg*4+3
    float bj0 = b[j4], bj1 = b[j4 + 1], bj2 = b[j4 + 2], bj3 = b[j4 + 3];
    float vs0 = 0.f, vs1 = 0.f, vs2 = 0.f, vs3 = 0.f;
    float vd0 = 0.f, vd1 = 0.f, vd2 = 0.f, vd3 = 0.f;
    if (MODE == 1) {
        vs0 = fold[j4]; vs1 = fold[j4 + 1]; vs2 = fold[j4 + 2]; vs3 = fold[j4 + 3];
        vd0 = fold[128 + j4]; vd1 = fold[128 + j4 + 1]; vd2 = fold[128 + j4 + 2]; vd3 = fold[128 + j4 + 3];
    }
    __syncthreads();
    float acc[4][4];
    #pragma unroll
    for (int p = 0; p < 4; p++) { acc[p][0] = bj0; acc[p][1] = bj1; acc[p][2] = bj2; acc[p][3] = bj3; }
    for (int k = 0; k < 128; k++) {
        float4 w4 = *(const float4*)&sW[k * 128 + j4];
        float4 rv = *(const float4*)&sT[k * 32 + ((rg ^ (k >> 4)) << 2)];
        acc[0][0] += rv.x * w4.x; acc[0][1] += rv.x * w4.y; acc[0][2] += rv.x * w4.z; acc[0][3] += rv.x * w4.w;
        acc[1][0] += rv.y * w4.x; acc[1][1] += rv.y * w4.y; acc[1][2] += rv.y * w4.z; acc[1][3] += rv.y * w4.w;
        acc[2][0] += rv.z * w4.x; acc[2][1] += rv.z * w4.y; acc[2][2] += rv.z * w4.z; acc[2][3] += rv.z * w4.w;
        acc[3][0] += rv.w * w4.x; acc[3][1] += rv.w * w4.y; acc[3][2] += rv.w * w4.z; acc[3][3] += rv.w * w4.w;
    }
    #pragma unroll
    for (int p = 0; p < 4; p++) {
        int row = r0 + rg * 4 + p;
        if (MODE == 0) {
            float ss_ = acc[p][0] * acc[p][0] + acc[p][1] * acc[p][1] +
                        acc[p][2] * acc[p][2] + acc[p][3] * acc[p][3];
            ss_ += __shfl_xor(ss_, 16); ss_ += __shfl_xor(ss_, 8);
            ss_ += __shfl_xor(ss_, 4);  ss_ += __shfl_xor(ss_, 2); ss_ += __shfl_xor(ss_, 1);
            float scale = 1.0f / fmaxf(sqrtf(ss_), 1e-12f);
            float o0 = acc[p][0] * scale, o1 = acc[p][1] * scale, o2 = acc[p][2] * scale, o3 = acc[p][3] * scale;
            *(float4*)&out[(size_t)row * 128 + j4] = make_float4(o0, o1, o2, o3);
            ushort4 u; u.x = f2bf(o0); u.y = f2bf(o1); u.z = f2bf(o2); u.w = f2bf(o3);
            ((ushort4*)out_bf)[(size_t)row * 32 + (j4 >> 2)] = u;
        } else {
            ushort4 u; u.x = f2bf(acc[p][0]); u.y = f2bf(acc[p][1]); u.z = f2bf(acc[p][2]); u.w = f2bf(acc[p][3]);
            ((ushort4*)out_bf)[(size_t)row * 32 + (j4 >> 2)] = u;
            float ps = acc[p][0] * vs0 + acc[p][1] * vs1 + acc[p][2] * vs2 + acc[p][3] * vs3;
            float pd = acc[p][0] * vd0 + acc[p][1] * vd1 + acc[p][2] * vd2 + acc[p][3] * vd3;
            ps += __shfl_xor(ps, 16); ps += __shfl_xor(ps, 8); ps += __shfl_xor(ps, 4);
            ps += __shfl_xor(ps, 2);  ps += __shfl_xor(ps, 1);
            pd += __shfl_xor(pd, 16); pd += __shfl_xor(pd, 8); pd += __shfl_xor(pd, 4);
            pd += __shfl_xor(pd, 2);  pd += __shfl_xor(pd, 1);
            if ((lane & 31) == 0) { a_src[row] = ps; a_dst[row] = pd; }
        }
    }
}

// ---------------- sparse GAT core: fused pass over bf16 z1, 4 edges in flight ----------------
__global__ __launch_bounds__(256) void k_att(const unsigned short* __restrict__ z1b,
                                             const int* __restrict__ offs,
                                             const int* __restrict__ csr_src,
                                             const float* __restrict__ a_src,
                                             const float* __restrict__ a_dst,
                                             const float* __restrict__ fold,
                                             float* __restrict__ r, int n) {
    int wave = (blockIdx.x * blockDim.x + threadIdx.x) >> 6;
    int lane = threadIdx.x & 63;
    if (wave >= n) return;
    int lo = offs[wave], hi = offs[wave + 1];
    float C0 = fold[256] + a_dst[wave];
    int half = lane >> 5, l32 = lane & 31;
    const ushort4* z4 = (const ushort4*)z1b;
    float4 acc = make_float4(0.f, 0.f, 0.f, 0.f);
    float den = 0.f;
    int i = lo + half;
    while (i + 6 < hi) {
        int s0 = csr_src[i], s1v = csr_src[i + 2], s2 = csr_src[i + 4], s3 = csr_src[i + 6];
        float a0 = a_src[s0], a1 = a_src[s1v], a2 = a_src[s2], a3 = a_src[s3];
        ushort4 v0 = z4[(size_t)s0 * 32 + l32];
        ushort4 v1 = z4[(size_t)s1v * 32 + l32];
        ushort4 v2 = z4[(size_t)s2 * 32 + l32];
        ushort4 v3 = z4[(size_t)s3 * 32 + l32];
        float e0 = a0 + C0; e0 = e0 > 0.f ? e0 : 0.01f * e0;
        float e1 = a1 + C0; e1 = e1 > 0.f ? e1 : 0.01f * e1;
        float e2 = a2 + C0; e2 = e2 > 0.f ? e2 : 0.01f * e2;
        float e3 = a3 + C0; e3 = e3 > 0.f ? e3 : 0.01f * e3;
        float al0 = __expf(fminf(e0, 60.f)), al1 = __expf(fminf(e1, 60.f));
        float al2 = __expf(fminf(e2, 60.f)), al3 = __expf(fminf(e3, 60.f));
        den += (al0 + al1) + (al2 + al3);
        acc.x += al0 * bfu(v0.x) + al1 * bfu(v1.x) + al2 * bfu(v2.x) + al3 * bfu(v3.x);
        acc.y += al0 * bfu(v0.y) + al1 * bfu(v1.y) + al2 * bfu(v2.y) + al3 * bfu(v3.y);
        acc.z += al0 * bfu(v0.z) + al1 * bfu(v1.z) + al2 * bfu(v2.z) + al3 * bfu(v3.z);
        acc.w += al0 * bfu(v0.w) + al1 * bfu(v1.w) + al2 * bfu(v2.w) + al3 * bfu(v3.w);
        i += 8;
    }
    while (i < hi) {
        int s = csr_src[i];
        float a = a_src[s];
        ushort4 v = z4[(size_t)s * 32 + l32];
        float e = a + C0; e = e > 0.f ? e : 0.01f * e;
        float al = __expf(fminf(e, 60.f));
        den += al;
        acc.x += al * bfu(v.x); acc.y += al * bfu(v.y);
        acc.z += al * bfu(v.z); acc.w += al * bfu(v.w);
        i += 2;
    }
    den += __shfl_xor(den, 32);
    acc.x += __shfl_xor(acc.x, 32);
    acc.y += __shfl_xor(acc.y, 32);
    acc.z += __shfl_xor(acc.z, 32);
    acc.w += __shfl_xor(acc.w, 32);
    if (half == 0) {
        float invden = 1.0f / den;
        float4 o = make_float4(acc.x * invden, acc.y * invden, acc.z * invden, acc.w * invden);
        ((float4*)r)[(size_t)wave * 32 + l32] = o;
    }
}

// ---------------- s1 = softmax(r @ Wa1 + ba1): one chunk/block, bf16 W copy, swizzled sT ----------------
__global__ __launch_bounds__(256) void k_s1(const float* __restrict__ r_,
                                            const unsigned short* __restrict__ Wa1b,
                                            const float* __restrict__ ba1,
                                            float* __restrict__ s1, int n) {
    __shared__ unsigned short sW2[128 * 256];  // 64 KB bf16 (raw copy, no cvt)
    __shared__ float sT[128 * 32];             // 16 KB swizzled
    int t = threadIdx.x;
    {
        // 128*256 ushorts = 4096 uint4; 256 threads x 16 iterations
        const uint4* g = (const uint4*)Wa1b;
        uint4* d = (uint4*)sW2;
        #pragma unroll
        for (int i = 0; i < 16; i++) d[t + i * 256] = g[t + i * 256];
    }
    int r0 = blockIdx.x * 32;
    {
        int lrow = t >> 3, seg = t & 7;
        const float4* g = (const float4*)&r_[(size_t)(r0 + lrow) * 128 + seg * 16];
        float4 v0 = g[0], v1 = g[1], v2 = g[2], v3 = g[3];
        int base = (((lrow >> 2) ^ seg) << 2) + (lrow & 3);
        int k0 = seg * 16;
        sT[(k0 + 0) * 32 + base] = v0.x; sT[(k0 + 1) * 32 + base] = v0.y;
        sT[(k0 + 2) * 32 + base] = v0.z; sT[(k0 + 3) * 32 + base] = v0.w;
        sT[(k0 + 4) * 32 + base] = v1.x; sT[(k0 + 5) * 32 + base] = v1.y;
        sT[(k0 + 6) * 32 + base] = v1.z; sT[(k0 + 7) * 32 + base] = v1.w;
        sT[(k0 + 8) * 32 + base] = v2.x; sT[(k0 + 9) * 32 + base] = v2.y;
        sT[(k0 + 10) * 32 + base] = v2.z; sT[(k0 + 11) * 32 + base] = v2.w;
        sT[(k0 + 12) * 32 + base] = v3.x; sT[(k0 + 13) * 32 + base] = v3.y;
        sT[(k0 + 14) * 32 + base] = v3.z; sT[(k0 + 15) * 32 + base] = v3.w;
    }
    int cg = t & 31, rg = t >> 5;
    int j8 = cg * 8;
    float bj[8];
    #pragma unroll
    for (int q = 0; q < 8; q++) bj[q] = ba1[j8 + q];
    __syncthreads();
    float acc[4][8];
    #pragma unroll
    for (int p = 0; p < 4; p++)
        #pragma unroll
        for (int q = 0; q < 8; q++) acc[p][q] = bj[q];
    for (int k = 0; k < 128; k++) {
        uint4 wz = *(const uint4*)&sW2[k * 256 + j8];
        float w0 = bf_lo(wz.x), w1 = bf_hi(wz.x), w2 = bf_lo(wz.y), w3 = bf_hi(wz.y);
        float w4 = bf_lo(wz.z), w5 = bf_hi(wz.z), w6 = bf_lo(wz.w), w7 = bf_hi(wz.w);
        float4 rv = *(const float4*)&sT[k * 32 + ((rg ^ (k >> 4)) << 2)];
        acc[0][0] += rv.x * w0; acc[0][1] += rv.x * w1; acc[0][2] += rv.x * w2; acc[0][3] += rv.x * w3;
        acc[0][4] += rv.x * w4; acc[0][5] += rv.x * w5; acc[0][6] += rv.x * w6; acc[0][7] += rv.x * w7;
        acc[1][0] += rv.y * w0; acc[1][1] += rv.y * w1; acc[1][2] += rv.y * w2; acc[1][3] += rv.y * w3;
        acc[1][4] += rv.y * w4; acc[1][5] += rv.y * w5; acc[1][6] += rv.y * w6; acc[1][7] += rv.y * w7;
        acc[2][0] += rv.z * w0; acc[2][1] += rv.z * w1; acc[2][2] += rv.z * w2; acc[2][3] += rv.z * w3;
        acc[2][4] += rv.z * w4; acc[2][5] += rv.z * w5; acc[2][6] += rv.z * w6; acc[2][7] += rv.z * w7;
        acc[3][0] += rv.w * w0; acc[3][1] += rv.w * w1; acc[3][2] += rv.w * w2; acc[3][3] += rv.w * w3;
        acc[3][4] += rv.w * w4; acc[3][5] += rv.w * w5; acc[3][6] += rv.w * w6; acc[3][7] += rv.w * w7;
    }
    #pragma unroll
    for (int p = 0; p < 4; p++) {
        int row = r0 + rg * 4 + p;
        float mx = acc[p][0];
        #pragma unroll
        for (int q = 1; q < 8; q++) mx = fmaxf(mx, acc[p][q]);
        mx = fmaxf(mx, __shfl_xor(mx, 16)); mx = fmaxf(mx, __shfl_xor(mx, 8));
        mx = fmaxf(mx, __shfl_xor(mx, 4));  mx = fmaxf(mx, __shfl_xor(mx, 2));
        mx = fmaxf(mx, __shfl_xor(mx, 1));
        float e[8], sm = 0.f;
        #pragma unroll
        for (int q = 0; q < 8; q++) { e[q] = __expf(acc[p][q] - mx); sm += e[q]; }
        sm += __shfl_xor(sm, 16); sm += __shfl_xor(sm, 8); sm += __shfl_xor(sm, 4);
        sm += __shfl_xor(sm, 2);  sm += __shfl_xor(sm, 1);
        float inv = 1.0f / sm;
        *(float4*)&s1[(size_t)row * 256 + j8]     = make_float4(e[0] * inv, e[1] * inv, e[2] * inv, e[3] * inv);
        *(float4*)&s1[(size_t)row * 256 + j8 + 4] = make_float4(e[4] * inv, e[5] * inv, e[6] * inv, e[7] * inv);
    }
}

// ---------------- x1 = s1^T @ z1: 256 blocks (128 row-splits x 2 col-halves), bf16 z ----------------
__global__ __launch_bounds__(512) void k_x1(const float* __restrict__ s1,
                                            const unsigned short* __restrict__ z1b,
                                            float* __restrict__ part, int n) {
    __shared__ float ss[16][128];            // 8 KB
    __shared__ unsigned short sz[16][128];   // 4 KB
    int t = threadIdx.x;
    int rs = blockIdx.x >> 1;
    int ch = blockIdx.x & 1;
    int c4 = (t & 31) * 4;
    int dg = t >> 5;
    int d0 = dg * 8;
    float a[4][8];
    #pragma unroll
    for (int c = 0; c < 4; c++)
        #pragma unroll
        for (int d = 0; d < 8; d++) a[c][d] = 0.f;
    int rows_per_block = (n + X1_SPLIT - 1) / X1_SPLIT;
    int row0 = rs * rows_per_block;
    int row_end = min(row0 + rows_per_block, n);
    int srow = t >> 5, scol4 = (t & 31) * 4;
    for (int r = row0; r < row_end; r += 16) {
        int nb = min(16, row_end - r);
        __syncthreads();
        if (srow < nb) {
            *(float4*)&ss[srow][scol4] = *(const float4*)&s1[(size_t)(r + srow) * 256 + ch * 128 + scol4];
            ((ushort4*)&sz[srow][0])[t & 31] = ((const ushort4*)z1b)[(size_t)(r + srow) * 32 + (t & 31)];
        }
        __syncthreads();
        for (int i = 0; i < nb; i++) {
            float4 sv = *(const float4*)&ss[i][c4];
            uint4 zz = *(const uint4*)&sz[i][d0];
            float zf[8];
            zf[0] = bf_lo(zz.x); zf[1] = bf_hi(zz.x); zf[2] = bf_lo(zz.y); zf[3] = bf_hi(zz.y);
            zf[4] = bf_lo(zz.z); zf[5] = bf_hi(zz.z); zf[6] = bf_lo(zz.w); zf[7] = bf_hi(zz.w);
            #pragma unroll
            for (int d = 0; d < 8; d++) {
                a[0][d] += sv.x * zf[d];
                a[1][d] += sv.y * zf[d];
                a[2][d] += sv.z * zf[d];
                a[3][d] += sv.w * zf[d];
            }
        }
    }
    size_t base = (size_t)rs * 32768 + (size_t)(ch * 128 + c4) * 128 + d0;
    #pragma unroll
    for (int c = 0; c < 4; c++) {
        *(float4*)&part[base + (size_t)c * 128]     = make_float4(a[c][0], a[c][1], a[c][2], a[c][3]);
        *(float4*)&part[base + (size_t)c * 128 + 4] = make_float4(a[c][4], a[c][5], a[c][6], a[c][7]);
    }
}

// ---------------- fused: x1 = reduce(part); lin2 = x1 @ We2 + be2 ----------------
__global__ __launch_bounds__(256) void k_lin2x(const float* __restrict__ part,
                                               const float* __restrict__ We2,
                                               const float* __restrict__ be2,
                                               float* __restrict__ x1,
                                               float* __restrict__ lin2) {
    int half = threadIdx.x >> 7, j = threadIdx.x & 127;
    int row = blockIdx.x * 2 + half;
    __shared__ float sr[2][128];
    float s = 0.f;
    const float* p = part + (size_t)row * 128 + j;
    #pragma unroll 8
    for (int q = 0; q < X1_SPLIT; q++) s += p[(size_t)q * 32768];
    x1[row * 128 + j] = s;
    sr[half][j] = s;
    __syncthreads();
    float acc = be2[j];
    #pragma unroll 8
    for (int k = 0; k < 128; k++) acc += sr[half][k] * We2[k * 128 + j];
    lin2[row * 128 + j] = acc;
}

// ---------------- coarse level ----------------
__global__ void k_coarse(const float* __restrict__ lin2, const float* __restrict__ Wa2,
                         const float* __restrict__ ba2,
                         float* __restrict__ s2, float* __restrict__ assign1,
                         float* __restrict__ x2, float* __restrict__ embed0) {
    __shared__ float mrow[128];
    __shared__ float p[32];
    __shared__ float red[2];
    int t = threadIdx.x; // 128 threads
    float s = 0.f;
    for (int i = 0; i < 256; i++) s += lin2[i * 128 + t];
    mrow[t] = s / 256.0f;
    __syncthreads();
    if (t < 32) {
        float z = ba2[t];
        for (int d = 0; d < 128; d++) z += mrow[d] * Wa2[d * 32 + t];
        float mx = z;
        for (int o = 16; o > 0; o >>= 1) mx = fmaxf(mx, __shfl_xor(mx, o, 32));
        float ex = __expf(z - mx);
        float sm = ex;
        for (int o = 16; o > 0; o >>= 1) sm += __shfl_xor(sm, o, 32);
        p[t] = ex / sm;
        assign1[t] = 1.0f;
    }
    __syncthreads();
    for (int i = t; i < 256 * 32; i += 128) s2[i] = p[i & 31];
    for (int i = t; i < 32 * 128; i += 128) {
        int k = i >> 7, d = i & 127;
        x2[i] = 256.0f * p[k] * mrow[d];
    }
    float tot = 0.f;
    for (int i = t; i < 32 * 128; i += 128) {
        int k = i >> 7, d = i & 127;
        tot += 256.0f * p[k] * mrow[d];
    }
    for (int o = 32; o > 0; o >>= 1) tot += __shfl_xor(tot, o);
    if ((t & 63) == 0) red[t >> 6] = tot;
    __syncthreads();
    if (t == 0) embed0[0] = (red[0] + red[1]) / 4096.0f;
}

extern "C" void kernel_launch(void* const* d_in, const int* in_sizes, int n_in,
                              void* d_out, int out_size, void* d_ws, size_t ws_size,
                              hipStream_t stream) {
    const float* feature = (const float*)d_in[0];
    const int*   eidx    = (const int*)d_in[1];
    const float* Wf   = (const float*)d_in[2];
    const float* bf   = (const float*)d_in[3];
    const float* We1  = (const float*)d_in[4];
    const float* be1  = (const float*)d_in[5];
    const float* Wa1  = (const float*)d_in[6];
    const float* ba1  = (const float*)d_in[7];
    const float* attW1= (const float*)d_in[8];
    const float* attb1= (const float*)d_in[9];
    const float* We2  = (const float*)d_in[10];
    const float* be2  = (const float*)d_in[11];
    const float* Wa2  = (const float*)d_in[12];
    const float* ba2  = (const float*)d_in[13];

    const int N = in_sizes[0] / DD;     // 20000
    const int E = in_sizes[1] / 2;      // 340000
    const int* src = eidx;
    const int* dst = eidx + E;

    // d_out layout
    float* out = (float*)d_out;
    float* s1_o      = out;
    float* s2_o      = s1_o + (size_t)N * CC1;
    float* assign1_o = s2_o + CC1 * CC2;
    float* embed3_o  = assign1_o + CC2;
    float* x1_o      = embed3_o + (size_t)N * DD;
    float* x2_o      = x1_o + CC1 * DD;
    float* embed0_o  = x2_o + CC2 * DD;

    // workspace carve (cnt and fill adjacent -> one memset)
    char* w = (char*)d_ws;
    auto alloc = [&](size_t bytes) { void* p = (void*)w; w += ((bytes + 255) / 256) * 256; return p; };
    int* cnt   = (int*)alloc((size_t)N * 4);
    int* fill  = (int*)alloc((size_t)N * 4);
    int* offs  = (int*)alloc((size_t)(N + 1) * 4);
    int* csr   = (int*)alloc((size_t)E * 4);
    float* fold = (float*)alloc(257 * 4);
    unsigned short* feat_bf = (unsigned short*)alloc((size_t)N * DD * 2);
    unsigned short* e3_bf   = (unsigned short*)alloc((size_t)N * DD * 2);
    unsigned short* z1b     = (unsigned short*)alloc((size_t)N * DD * 2);
    unsigned short* Wa1b    = (unsigned short*)alloc((size_t)128 * 256 * 2);
    float* a_src = (float*)alloc((size_t)N * 4);
    float* a_dst = (float*)alloc((size_t)N * 4);
    float* lin2  = (float*)alloc((size_t)CC1 * DD * 4);
    size_t agg_bytes = (size_t)N * DD * 4;
    size_t part_bytes = (size_t)X1_SPLIT * CC1 * DD * 4;   // 16.78 MB
    float* agg  = (float*)alloc(agg_bytes > part_bytes ? agg_bytes : part_bytes);
    float* part = agg;   // agg (r) dead by the time k_x1 runs

    hipMemsetAsync(cnt, 0, ((size_t)N * 4 + 255) / 256 * 256 + (size_t)N * 4, stream); // covers cnt+fill

    k_count<<<(E + 255) / 256, 256, 0, stream>>>(dst, cnt, E);
    k_scan<<<1, 1024, 0, stream>>>(cnt, offs, N);
    k_fill<<<(E + 255) / 256, 256, 0, stream>>>(src, dst, offs, fill, csr, E);
    int nf4 = N * DD / 4;
    int prepBlocks = (nf4 + 128 * 256 / 4 + 255) / 256;
    k_prepfold<<<prepBlocks + 1, 256, 0, stream>>>(feature, Wa1, ba1, attW1, attb1,
                                                   feat_bf, Wa1b, fold, nf4, prepBlocks);

    int chunkBlocks = N / 32;   // 625, exact
    // embed3 = normalize(mean(feat_bf) @ Wf + bf)  [fused gather+GEMM]
    k_mgemm<0><<<chunkBlocks, 256, 0, stream>>>(feat_bf, offs, csr, Wf, bf,
                                                embed3_o, e3_bf, nullptr, nullptr, nullptr, N);
    // z1 (bf16) = mean(e3_bf) @ We1 + be1 ; a_src/a_dst  [fused gather+GEMM]
    k_mgemm<1><<<chunkBlocks, 256, 0, stream>>>(e3_bf, offs, csr, We1, be1,
                                                nullptr, z1b, fold, a_src, a_dst, N);
    // attention -> r (agg)
    int segBlocks = (N + 3) / 4;
    k_att<<<segBlocks, 256, 0, stream>>>(z1b, offs, csr, a_src, a_dst, fold, agg, N);
    // s1 = softmax(r @ Wa1 + ba1)
    k_s1<<<chunkBlocks, 256, 0, stream>>>(agg, Wa1b, ba1, s1_o, N);
    // x1 = s1^T @ z1 (partials)
    k_x1<<<2 * X1_SPLIT, 512, 0, stream>>>(s1_o, z1b, part, N);
    // x1 reduce + lin2 fused
    k_lin2x<<<CC1 / 2, 256, 0, stream>>>(part, We2, be2, x1_o, lin2);
    // coarse outputs
    k_coarse<<<1, 128, 0, stream>>>(lin2, Wa2, ba2, s2_o, assign1_o, x2_o, embed0_o);
}

// Round 9
// 345.260 us; speedup vs baseline: 1.1456x; 1.1456x over previous
//
#include <hip/hip_runtime.h>
#include <hip/hip_bf16.h>
#include <math.h>

#define NN 20000
#define DD 128
#define CC1 256
#define CC2 32
#define X1_SPLIT 128

__device__ __forceinline__ unsigned short f2bf(float f) {
    unsigned int b = __float_as_uint(f);
    b = (b + 0x7fffu + ((b >> 16) & 1u)) >> 16;
    return (unsigned short)b;
}
__device__ __forceinline__ float bfu(unsigned short u) { return __uint_as_float((unsigned int)u << 16); }
__device__ __forceinline__ float bf_lo(unsigned int u) { return __uint_as_float(u << 16); }
__device__ __forceinline__ float bf_hi(unsigned int u) { return __uint_as_float(u & 0xffff0000u); }

// ---------------- fused: edge count + bf16 prep + attW1 fold (block-range split) ----------------
__global__ __launch_bounds__(256) void k_countprep(const int* __restrict__ dst,
                                                   int* __restrict__ cnt, int E,
                                                   const float* __restrict__ feature,
                                                   const float* __restrict__ Wa1,
                                                   const float* __restrict__ ba1,
                                                   const float* __restrict__ attW1,
                                                   const float* __restrict__ attb1,
                                                   unsigned short* __restrict__ feat_bf,
                                                   unsigned short* __restrict__ Wa1b,
                                                   float* __restrict__ fold,
                                                   int nf4, int countBlocks, int prepBlocks) {
    int b = blockIdx.x;
    int t = threadIdx.x;
    if (b < countBlocks) {
        int e = b * 256 + t;
        if (e < E) atomicAdd(&cnt[dst[e]], 1);
        return;
    }
    b -= countBlocks;
    if (b < prepBlocks) {
        int i = b * 256 + t;
        int tot = nf4 + 128 * 256 / 4;
        if (i >= tot) return;
        float4 v;
        if (i < nf4) v = ((const float4*)feature)[i];
        else         v = ((const float4*)Wa1)[i - nf4];
        ushort4 u;
        u.x = f2bf(v.x); u.y = f2bf(v.y); u.z = f2bf(v.z); u.w = f2bf(v.w);
        if (i < nf4) ((ushort4*)feat_bf)[i] = u;
        else         ((ushort4*)Wa1b)[i - nf4] = u;
        return;
    }
    // fold block
    if (t < 128) {
        float vs = 0.f, vd = 0.f;
        for (int k = 0; k < CC1; k++) {
            float w = Wa1[t * CC1 + k];
            vs += w * attW1[k];
            vd += w * attW1[CC1 + k];
        }
        fold[t] = vs;
        fold[128 + t] = vd;
        if (t == 0) {
            float c = attb1[0];
            for (int k = 0; k < CC1; k++) c += ba1[k] * (attW1[k] + attW1[CC1 + k]);
            fold[256] = c;
        }
    }
}

__global__ void k_scan(const int* __restrict__ cnt, int* __restrict__ offs, int n) {
    __shared__ int part[1024];
    int t = threadIdx.x;
    int chunk = (n + 1023) / 1024;
    int lo = t * chunk, hi = min(lo + chunk, n);
    int s = 0;
    for (int i = lo; i < hi; i++) s += cnt[i];
    part[t] = s;
    __syncthreads();
    for (int d = 1; d < 1024; d <<= 1) {
        int v = (t >= d) ? part[t - d] : 0;
        __syncthreads();
        part[t] += v;
        __syncthreads();
    }
    int base = (t > 0) ? part[t - 1] : 0;
    for (int i = lo; i < hi; i++) { offs[i] = base; base += cnt[i]; }
    if (t == 1023) offs[n] = part[1023];
}

__global__ void k_fill(const int* __restrict__ src, const int* __restrict__ dst,
                       const int* __restrict__ offs, int* __restrict__ fill,
                       int* __restrict__ csr_src, int E) {
    int e = blockIdx.x * blockDim.x + threadIdx.x;
    if (e < E) {
        int d = dst[e];
        int pos = atomicAdd(&fill[d], 1);
        csr_src[offs[d] + pos] = src[e];
    }
}

// ---------------- per-dst mean over bf16 rows: one wave per node, 4 edges in flight ----------------
__global__ __launch_bounds__(256) void k_seg_mean_bf(const unsigned short* __restrict__ in,
                                                     const int* __restrict__ offs,
                                                     const int* __restrict__ csr_src,
                                                     float* __restrict__ out, int n) {
    int wave = (blockIdx.x * blockDim.x + threadIdx.x) >> 6;
    int lane = threadIdx.x & 63;
    if (wave >= n) return;
    int lo = offs[wave], hi = offs[wave + 1];
    int half = lane >> 5, l32 = lane & 31;
    const ushort4* f = (const ushort4*)in;
    float4 acc = make_float4(0.f, 0.f, 0.f, 0.f);
    int i = lo + half;
    while (i + 6 < hi) {
        int s0 = csr_src[i], s1v = csr_src[i + 2], s2 = csr_src[i + 4], s3 = csr_src[i + 6];
        ushort4 v0 = f[(size_t)s0 * 32 + l32];
        ushort4 v1 = f[(size_t)s1v * 32 + l32];
        ushort4 v2 = f[(size_t)s2 * 32 + l32];
        ushort4 v3 = f[(size_t)s3 * 32 + l32];
        acc.x += bfu(v0.x) + bfu(v1.x) + bfu(v2.x) + bfu(v3.x);
        acc.y += bfu(v0.y) + bfu(v1.y) + bfu(v2.y) + bfu(v3.y);
        acc.z += bfu(v0.z) + bfu(v1.z) + bfu(v2.z) + bfu(v3.z);
        acc.w += bfu(v0.w) + bfu(v1.w) + bfu(v2.w) + bfu(v3.w);
        i += 8;
    }
    while (i < hi) {
        ushort4 v = f[(size_t)csr_src[i] * 32 + l32];
        acc.x += bfu(v.x); acc.y += bfu(v.y); acc.z += bfu(v.z); acc.w += bfu(v.w);
        i += 2;
    }
    acc.x += __shfl_xor(acc.x, 32);
    acc.y += __shfl_xor(acc.y, 32);
    acc.z += __shfl_xor(acc.z, 32);
    acc.w += __shfl_xor(acc.w, 32);
    if (half == 0) {
        float inv = 1.0f / (float)max(hi - lo, 1);
        float4 r = make_float4(acc.x * inv, acc.y * inv, acc.z * inv, acc.w * inv);
        ((float4*)out)[(size_t)wave * 32 + l32] = r;
    }
}

// ---------------- row GEMM [n,128]x[128,128]: one 32-row chunk/block, swizzled sT ----------------
// MODE 0: L2-normalize rows -> out f32 + out_bf
// MODE 1: out_bf only (z1 bf16); a_src/a_dst via folded attention vectors
template <int MODE>
__global__ __launch_bounds__(256) void k_gemm128(const float* __restrict__ in,
                                                 const float* __restrict__ W,
                                                 const float* __restrict__ b,
                                                 float* __restrict__ out,
                                                 unsigned short* __restrict__ out_bf,
                                                 const float* __restrict__ fold,
                                                 float* __restrict__ a_src,
                                                 float* __restrict__ a_dst, int n) {
    __shared__ float sW[128 * 128];   // 64 KB
    __shared__ float sT[128 * 32];    // 16 KB, swizzled transposed activations
    int t = threadIdx.x;
    for (int i = t; i < 4096; i += 256) ((float4*)sW)[i] = ((const float4*)W)[i];
    int r0 = blockIdx.x * 32;
    {
        int lrow = t >> 3, seg = t & 7;
        const float4* g = (const float4*)&in[(size_t)(r0 + lrow) * 128 + seg * 16];
        float4 v0 = g[0], v1 = g[1], v2 = g[2], v3 = g[3];
        int base = (((lrow >> 2) ^ seg) << 2) + (lrow & 3);
        int k0 = seg * 16;
        sT[(k0 + 0) * 32 + base] = v0.x; sT[(k0 + 1) * 32 + base] = v0.y;
        sT[(k0 + 2) * 32 + base] = v0.z; sT[(k0 + 3) * 32 + base] = v0.w;
        sT[(k0 + 4) * 32 + base] = v1.x; sT[(k0 + 5) * 32 + base] = v1.y;
        sT[(k0 + 6) * 32 + base] = v1.z; sT[(k0 + 7) * 32 + base] = v1.w;
        sT[(k0 + 8) * 32 + base] = v2.x; sT[(k0 + 9) * 32 + base] = v2.y;
        sT[(k0 + 10) * 32 + base] = v2.z; sT[(k0 + 11) * 32 + base] = v2.w;
        sT[(k0 + 12) * 32 + base] = v3.x; sT[(k0 + 13) * 32 + base] = v3.y;
        sT[(k0 + 14) * 32 + base] = v3.z; sT[(k0 + 15) * 32 + base] = v3.w;
    }
    int lane = t & 63;
    int wv = t >> 6;
    int j4 = (lane & 31) * 4;
    int rg = wv * 2 + (lane >> 5);    // 0..7 -> rows rg*4..rg*4+3
    float bj0 = b[j4], bj1 = b[j4 + 1], bj2 = b[j4 + 2], bj3 = b[j4 + 3];
    float vs0 = 0.f, vs1 = 0.f, vs2 = 0.f, vs3 = 0.f;
    float vd0 = 0.f, vd1 = 0.f, vd2 = 0.f, vd3 = 0.f;
    if (MODE == 1) {
        vs0 = fold[j4]; vs1 = fold[j4 + 1]; vs2 = fold[j4 + 2]; vs3 = fold[j4 + 3];
        vd0 = fold[128 + j4]; vd1 = fold[128 + j4 + 1]; vd2 = fold[128 + j4 + 2]; vd3 = fold[128 + j4 + 3];
    }
    __syncthreads();
    float acc[4][4];
    #pragma unroll
    for (int p = 0; p < 4; p++) { acc[p][0] = bj0; acc[p][1] = bj1; acc[p][2] = bj2; acc[p][3] = bj3; }
    for (int k = 0; k < 128; k++) {
        float4 w4 = *(const float4*)&sW[k * 128 + j4];
        float4 rv = *(const float4*)&sT[k * 32 + ((rg ^ (k >> 4)) << 2)];
        acc[0][0] += rv.x * w4.x; acc[0][1] += rv.x * w4.y; acc[0][2] += rv.x * w4.z; acc[0][3] += rv.x * w4.w;
        acc[1][0] += rv.y * w4.x; acc[1][1] += rv.y * w4.y; acc[1][2] += rv.y * w4.z; acc[1][3] += rv.y * w4.w;
        acc[2][0] += rv.z * w4.x; acc[2][1] += rv.z * w4.y; acc[2][2] += rv.z * w4.z; acc[2][3] += rv.z * w4.w;
        acc[3][0] += rv.w * w4.x; acc[3][1] += rv.w * w4.y; acc[3][2] += rv.w * w4.z; acc[3][3] += rv.w * w4.w;
    }
    #pragma unroll
    for (int p = 0; p < 4; p++) {
        int row = r0 + rg * 4 + p;
        if (MODE == 0) {
            float ss_ = acc[p][0] * acc[p][0] + acc[p][1] * acc[p][1] +
                        acc[p][2] * acc[p][2] + acc[p][3] * acc[p][3];
            ss_ += __shfl_xor(ss_, 16); ss_ += __shfl_xor(ss_, 8);
            ss_ += __shfl_xor(ss_, 4);  ss_ += __shfl_xor(ss_, 2); ss_ += __shfl_xor(ss_, 1);
            float scale = 1.0f / fmaxf(sqrtf(ss_), 1e-12f);
            float o0 = acc[p][0] * scale, o1 = acc[p][1] * scale, o2 = acc[p][2] * scale, o3 = acc[p][3] * scale;
            *(float4*)&out[(size_t)row * 128 + j4] = make_float4(o0, o1, o2, o3);
            ushort4 u; u.x = f2bf(o0); u.y = f2bf(o1); u.z = f2bf(o2); u.w = f2bf(o3);
            ((ushort4*)out_bf)[(size_t)row * 32 + (j4 >> 2)] = u;
        } else {
            ushort4 u; u.x = f2bf(acc[p][0]); u.y = f2bf(acc[p][1]); u.z = f2bf(acc[p][2]); u.w = f2bf(acc[p][3]);
            ((ushort4*)out_bf)[(size_t)row * 32 + (j4 >> 2)] = u;
            float ps = acc[p][0] * vs0 + acc[p][1] * vs1 + acc[p][2] * vs2 + acc[p][3] * vs3;
            float pd = acc[p][0] * vd0 + acc[p][1] * vd1 + acc[p][2] * vd2 + acc[p][3] * vd3;
            ps += __shfl_xor(ps, 16); ps += __shfl_xor(ps, 8); ps += __shfl_xor(ps, 4);
            ps += __shfl_xor(ps, 2);  ps += __shfl_xor(ps, 1);
            pd += __shfl_xor(pd, 16); pd += __shfl_xor(pd, 8); pd += __shfl_xor(pd, 4);
            pd += __shfl_xor(pd, 2);  pd += __shfl_xor(pd, 1);
            if ((lane & 31) == 0) { a_src[row] = ps; a_dst[row] = pd; }
        }
    }
}

// ---------------- sparse GAT core: fused pass over bf16 z1, 4 edges in flight ----------------
__global__ __launch_bounds__(256) void k_att(const unsigned short* __restrict__ z1b,
                                             const int* __restrict__ offs,
                                             const int* __restrict__ csr_src,
                                             const float* __restrict__ a_src,
                                             const float* __restrict__ a_dst,
                                             const float* __restrict__ fold,
                                             float* __restrict__ r, int n) {
    int wave = (blockIdx.x * blockDim.x + threadIdx.x) >> 6;
    int lane = threadIdx.x & 63;
    if (wave >= n) return;
    int lo = offs[wave], hi = offs[wave + 1];
    float C0 = fold[256] + a_dst[wave];
    int half = lane >> 5, l32 = lane & 31;
    const ushort4* z4 = (const ushort4*)z1b;
    float4 acc = make_float4(0.f, 0.f, 0.f, 0.f);
    float den = 0.f;
    int i = lo + half;
    while (i + 6 < hi) {
        int s0 = csr_src[i], s1v = csr_src[i + 2], s2 = csr_src[i + 4], s3 = csr_src[i + 6];
        float a0 = a_src[s0], a1 = a_src[s1v], a2 = a_src[s2], a3 = a_src[s3];
        ushort4 v0 = z4[(size_t)s0 * 32 + l32];
        ushort4 v1 = z4[(size_t)s1v * 32 + l32];
        ushort4 v2 = z4[(size_t)s2 * 32 + l32];
        ushort4 v3 = z4[(size_t)s3 * 32 + l32];
        float e0 = a0 + C0; e0 = e0 > 0.f ? e0 : 0.01f * e0;
        float e1 = a1 + C0; e1 = e1 > 0.f ? e1 : 0.01f * e1;
        float e2 = a2 + C0; e2 = e2 > 0.f ? e2 : 0.01f * e2;
        float e3 = a3 + C0; e3 = e3 > 0.f ? e3 : 0.01f * e3;
        float al0 = __expf(fminf(e0, 60.f)), al1 = __expf(fminf(e1, 60.f));
        float al2 = __expf(fminf(e2, 60.f)), al3 = __expf(fminf(e3, 60.f));
        den += (al0 + al1) + (al2 + al3);
        acc.x += al0 * bfu(v0.x) + al1 * bfu(v1.x) + al2 * bfu(v2.x) + al3 * bfu(v3.x);
        acc.y += al0 * bfu(v0.y) + al1 * bfu(v1.y) + al2 * bfu(v2.y) + al3 * bfu(v3.y);
        acc.z += al0 * bfu(v0.z) + al1 * bfu(v1.z) + al2 * bfu(v2.z) + al3 * bfu(v3.z);
        acc.w += al0 * bfu(v0.w) + al1 * bfu(v1.w) + al2 * bfu(v2.w) + al3 * bfu(v3.w);
        i += 8;
    }
    while (i < hi) {
        int s = csr_src[i];
        float a = a_src[s];
        ushort4 v = z4[(size_t)s * 32 + l32];
        float e = a + C0; e = e > 0.f ? e : 0.01f * e;
        float al = __expf(fminf(e, 60.f));
        den += al;
        acc.x += al * bfu(v.x); acc.y += al * bfu(v.y);
        acc.z += al * bfu(v.z); acc.w += al * bfu(v.w);
        i += 2;
    }
    den += __shfl_xor(den, 32);
    acc.x += __shfl_xor(acc.x, 32);
    acc.y += __shfl_xor(acc.y, 32);
    acc.z += __shfl_xor(acc.z, 32);
    acc.w += __shfl_xor(acc.w, 32);
    if (half == 0) {
        float invden = 1.0f / den;
        float4 o = make_float4(acc.x * invden, acc.y * invden, acc.z * invden, acc.w * invden);
        ((float4*)r)[(size_t)wave * 32 + l32] = o;
    }
}

// ---------------- s1 = softmax(r @ Wa1 + ba1): one chunk/block, bf16 W copy, swizzled sT ----------------
__global__ __launch_bounds__(256) void k_s1(const float* __restrict__ r_,
                                            const unsigned short* __restrict__ Wa1b,
                                            const float* __restrict__ ba1,
                                            float* __restrict__ s1, int n) {
    __shared__ unsigned short sW2[128 * 256];  // 64 KB bf16 (raw copy, no cvt)
    __shared__ float sT[128 * 32];             // 16 KB swizzled
    int t = threadIdx.x;
    {
        // 128*256 ushorts = 4096 uint4; 256 threads x 16 iterations
        const uint4* g = (const uint4*)Wa1b;
        uint4* d = (uint4*)sW2;
        #pragma unroll
        for (int i = 0; i < 16; i++) d[t + i * 256] = g[t + i * 256];
    }
    int r0 = blockIdx.x * 32;
    {
        int lrow = t >> 3, seg = t & 7;
        const float4* g = (const float4*)&r_[(size_t)(r0 + lrow) * 128 + seg * 16];
        float4 v0 = g[0], v1 = g[1], v2 = g[2], v3 = g[3];
        int base = (((lrow >> 2) ^ seg) << 2) + (lrow & 3);
        int k0 = seg * 16;
        sT[(k0 + 0) * 32 + base] = v0.x; sT[(k0 + 1) * 32 + base] = v0.y;
        sT[(k0 + 2) * 32 + base] = v0.z; sT[(k0 + 3) * 32 + base] = v0.w;
        sT[(k0 + 4) * 32 + base] = v1.x; sT[(k0 + 5) * 32 + base] = v1.y;
        sT[(k0 + 6) * 32 + base] = v1.z; sT[(k0 + 7) * 32 + base] = v1.w;
        sT[(k0 + 8) * 32 + base] = v2.x; sT[(k0 + 9) * 32 + base] = v2.y;
        sT[(k0 + 10) * 32 + base] = v2.z; sT[(k0 + 11) * 32 + base] = v2.w;
        sT[(k0 + 12) * 32 + base] = v3.x; sT[(k0 + 13) * 32 + base] = v3.y;
        sT[(k0 + 14) * 32 + base] = v3.z; sT[(k0 + 15) * 32 + base] = v3.w;
    }
    int cg = t & 31, rg = t >> 5;
    int j8 = cg * 8;
    float bj[8];
    #pragma unroll
    for (int q = 0; q < 8; q++) bj[q] = ba1[j8 + q];
    __syncthreads();
    float acc[4][8];
    #pragma unroll
    for (int p = 0; p < 4; p++)
        #pragma unroll
        for (int q = 0; q < 8; q++) acc[p][q] = bj[q];
    for (int k = 0; k < 128; k++) {
        uint4 wz = *(const uint4*)&sW2[k * 256 + j8];
        float w0 = bf_lo(wz.x), w1 = bf_hi(wz.x), w2 = bf_lo(wz.y), w3 = bf_hi(wz.y);
        float w4 = bf_lo(wz.z), w5 = bf_hi(wz.z), w6 = bf_lo(wz.w), w7 = bf_hi(wz.w);
        float4 rv = *(const float4*)&sT[k * 32 + ((rg ^ (k >> 4)) << 2)];
        acc[0][0] += rv.x * w0; acc[0][1] += rv.x * w1; acc[0][2] += rv.x * w2; acc[0][3] += rv.x * w3;
        acc[0][4] += rv.x * w4; acc[0][5] += rv.x * w5; acc[0][6] += rv.x * w6; acc[0][7] += rv.x * w7;
        acc[1][0] += rv.y * w0; acc[1][1] += rv.y * w1; acc[1][2] += rv.y * w2; acc[1][3] += rv.y * w3;
        acc[1][4] += rv.y * w4; acc[1][5] += rv.y * w5; acc[1][6] += rv.y * w6; acc[1][7] += rv.y * w7;
        acc[2][0] += rv.z * w0; acc[2][1] += rv.z * w1; acc[2][2] += rv.z * w2; acc[2][3] += rv.z * w3;
        acc[2][4] += rv.z * w4; acc[2][5] += rv.z * w5; acc[2][6] += rv.z * w6; acc[2][7] += rv.z * w7;
        acc[3][0] += rv.w * w0; acc[3][1] += rv.w * w1; acc[3][2] += rv.w * w2; acc[3][3] += rv.w * w3;
        acc[3][4] += rv.w * w4; acc[3][5] += rv.w * w5; acc[3][6] += rv.w * w6; acc[3][7] += rv.w * w7;
    }
    #pragma unroll
    for (int p = 0; p < 4; p++) {
        int row = r0 + rg * 4 + p;
        float mx = acc[p][0];
        #pragma unroll
        for (int q = 1; q < 8; q++) mx = fmaxf(mx, acc[p][q]);
        mx = fmaxf(mx, __shfl_xor(mx, 16)); mx = fmaxf(mx, __shfl_xor(mx, 8));
        mx = fmaxf(mx, __shfl_xor(mx, 4));  mx = fmaxf(mx, __shfl_xor(mx, 2));
        mx = fmaxf(mx, __shfl_xor(mx, 1));
        float e[8], sm = 0.f;
        #pragma unroll
        for (int q = 0; q < 8; q++) { e[q] = __expf(acc[p][q] - mx); sm += e[q]; }
        sm += __shfl_xor(sm, 16); sm += __shfl_xor(sm, 8); sm += __shfl_xor(sm, 4);
        sm += __shfl_xor(sm, 2);  sm += __shfl_xor(sm, 1);
        float inv = 1.0f / sm;
        *(float4*)&s1[(size_t)row * 256 + j8]     = make_float4(e[0] * inv, e[1] * inv, e[2] * inv, e[3] * inv);
        *(float4*)&s1[(size_t)row * 256 + j8 + 4] = make_float4(e[4] * inv, e[5] * inv, e[6] * inv, e[7] * inv);
    }
}

// ---------------- x1 = s1^T @ z1: 256 blocks (128 row-splits x 2 col-halves), bf16 z ----------------
__global__ __launch_bounds__(512) void k_x1(const float* __restrict__ s1,
                                            const unsigned short* __restrict__ z1b,
                                            float* __restrict__ part, int n) {
    __shared__ float ss[16][128];            // 8 KB
    __shared__ unsigned short sz[16][128];   // 4 KB
    int t = threadIdx.x;
    int rs = blockIdx.x >> 1;
    int ch = blockIdx.x & 1;
    int c4 = (t & 31) * 4;
    int dg = t >> 5;
    int d0 = dg * 8;
    float a[4][8];
    #pragma unroll
    for (int c = 0; c < 4; c++)
        #pragma unroll
        for (int d = 0; d < 8; d++) a[c][d] = 0.f;
    int rows_per_block = (n + X1_SPLIT - 1) / X1_SPLIT;
    int row0 = rs * rows_per_block;
    int row_end = min(row0 + rows_per_block, n);
    int srow = t >> 5, scol4 = (t & 31) * 4;
    for (int r = row0; r < row_end; r += 16) {
        int nb = min(16, row_end - r);
        __syncthreads();
        if (srow < nb) {
            *(float4*)&ss[srow][scol4] = *(const float4*)&s1[(size_t)(r + srow) * 256 + ch * 128 + scol4];
            ((ushort4*)&sz[srow][0])[t & 31] = ((const ushort4*)z1b)[(size_t)(r + srow) * 32 + (t & 31)];
        }
        __syncthreads();
        for (int i = 0; i < nb; i++) {
            float4 sv = *(const float4*)&ss[i][c4];
            uint4 zz = *(const uint4*)&sz[i][d0];
            float zf[8];
            zf[0] = bf_lo(zz.x); zf[1] = bf_hi(zz.x); zf[2] = bf_lo(zz.y); zf[3] = bf_hi(zz.y);
            zf[4] = bf_lo(zz.z); zf[5] = bf_hi(zz.z); zf[6] = bf_lo(zz.w); zf[7] = bf_hi(zz.w);
            #pragma unroll
            for (int d = 0; d < 8; d++) {
                a[0][d] += sv.x * zf[d];
                a[1][d] += sv.y * zf[d];
                a[2][d] += sv.z * zf[d];
                a[3][d] += sv.w * zf[d];
            }
        }
    }
    size_t base = (size_t)rs * 32768 + (size_t)(ch * 128 + c4) * 128 + d0;
    #pragma unroll
    for (int c = 0; c < 4; c++) {
        *(float4*)&part[base + (size_t)c * 128]     = make_float4(a[c][0], a[c][1], a[c][2], a[c][3]);
        *(float4*)&part[base + (size_t)c * 128 + 4] = make_float4(a[c][4], a[c][5], a[c][6], a[c][7]);
    }
}

// ---------------- fused: x1 = reduce(part); lin2 = x1 @ We2 + be2 ----------------
__global__ __launch_bounds__(256) void k_lin2x(const float* __restrict__ part,
                                               const float* __restrict__ We2,
                                               const float* __restrict__ be2,
                                               float* __restrict__ x1,
                                               float* __restrict__ lin2) {
    int half = threadIdx.x >> 7, j = threadIdx.x & 127;
    int row = blockIdx.x * 2 + half;
    __shared__ float sr[2][128];
    float s = 0.f;
    const float* p = part + (size_t)row * 128 + j;
    #pragma unroll 8
    for (int q = 0; q < X1_SPLIT; q++) s += p[(size_t)q * 32768];
    x1[row * 128 + j] = s;
    sr[half][j] = s;
    __syncthreads();
    float acc = be2[j];
    #pragma unroll 8
    for (int k = 0; k < 128; k++) acc += sr[half][k] * We2[k * 128 + j];
    lin2[row * 128 + j] = acc;
}

// ---------------- coarse level ----------------
__global__ void k_coarse(const float* __restrict__ lin2, const float* __restrict__ Wa2,
                         const float* __restrict__ ba2,
                         float* __restrict__ s2, float* __restrict__ assign1,
                         float* __restrict__ x2, float* __restrict__ embed0) {
    __shared__ float mrow[128];
    __shared__ float p[32];
    __shared__ float red[2];
    int t = threadIdx.x; // 128 threads
    float s = 0.f;
    for (int i = 0; i < 256; i++) s += lin2[i * 128 + t];
    mrow[t] = s / 256.0f;
    __syncthreads();
    if (t < 32) {
        float z = ba2[t];
        for (int d = 0; d < 128; d++) z += mrow[d] * Wa2[d * 32 + t];
        float mx = z;
        for (int o = 16; o > 0; o >>= 1) mx = fmaxf(mx, __shfl_xor(mx, o, 32));
        float ex = __expf(z - mx);
        float sm = ex;
        for (int o = 16; o > 0; o >>= 1) sm += __shfl_xor(sm, o, 32);
        p[t] = ex / sm;
        assign1[t] = 1.0f;
    }
    __syncthreads();
    for (int i = t; i < 256 * 32; i += 128) s2[i] = p[i & 31];
    for (int i = t; i < 32 * 128; i += 128) {
        int k = i >> 7, d = i & 127;
        x2[i] = 256.0f * p[k] * mrow[d];
    }
    float tot = 0.f;
    for (int i = t; i < 32 * 128; i += 128) {
        int k = i >> 7, d = i & 127;
        tot += 256.0f * p[k] * mrow[d];
    }
    for (int o = 32; o > 0; o >>= 1) tot += __shfl_xor(tot, o);
    if ((t & 63) == 0) red[t >> 6] = tot;
    __syncthreads();
    if (t == 0) embed0[0] = (red[0] + red[1]) / 4096.0f;
}

extern "C" void kernel_launch(void* const* d_in, const int* in_sizes, int n_in,
                              void* d_out, int out_size, void* d_ws, size_t ws_size,
                              hipStream_t stream) {
    const float* feature = (const float*)d_in[0];
    const int*   eidx    = (const int*)d_in[1];
    const float* Wf   = (const float*)d_in[2];
    const float* bf   = (const float*)d_in[3];
    const float* We1  = (const float*)d_in[4];
    const float* be1  = (const float*)d_in[5];
    const float* Wa1  = (const float*)d_in[6];
    const float* ba1  = (const float*)d_in[7];
    const float* attW1= (const float*)d_in[8];
    const float* attb1= (const float*)d_in[9];
    const float* We2  = (const float*)d_in[10];
    const float* be2  = (const float*)d_in[11];
    const float* Wa2  = (const float*)d_in[12];
    const float* ba2  = (const float*)d_in[13];

    const int N = in_sizes[0] / DD;     // 20000
    const int E = in_sizes[1] / 2;      // 340000
    const int* src = eidx;
    const int* dst = eidx + E;

    // d_out layout
    float* out = (float*)d_out;
    float* s1_o      = out;
    float* s2_o      = s1_o + (size_t)N * CC1;
    float* assign1_o = s2_o + CC1 * CC2;
    float* embed3_o  = assign1_o + CC2;
    float* x1_o      = embed3_o + (size_t)N * DD;
    float* x2_o      = x1_o + CC1 * DD;
    float* embed0_o  = x2_o + CC2 * DD;

    // workspace carve (cnt and fill adjacent -> one memset)
    char* w = (char*)d_ws;
    auto alloc = [&](size_t bytes) { void* p = (void*)w; w += ((bytes + 255) / 256) * 256; return p; };
    int* cnt   = (int*)alloc((size_t)N * 4);
    int* fill  = (int*)alloc((size_t)N * 4);
    int* offs  = (int*)alloc((size_t)(N + 1) * 4);
    int* csr   = (int*)alloc((size_t)E * 4);
    float* fold = (float*)alloc(257 * 4);
    unsigned short* feat_bf = (unsigned short*)alloc((size_t)N * DD * 2);
    unsigned short* e3_bf   = (unsigned short*)alloc((size_t)N * DD * 2);
    unsigned short* z1b     = (unsigned short*)alloc((size_t)N * DD * 2);
    unsigned short* Wa1b    = (unsigned short*)alloc((size_t)128 * 256 * 2);
    float* a_src = (float*)alloc((size_t)N * 4);
    float* a_dst = (float*)alloc((size_t)N * 4);
    float* lin2  = (float*)alloc((size_t)CC1 * DD * 4);
    size_t agg_bytes = (size_t)N * DD * 4;
    size_t part_bytes = (size_t)X1_SPLIT * CC1 * DD * 4;   // 16.78 MB
    float* agg  = (float*)alloc(agg_bytes > part_bytes ? agg_bytes : part_bytes);
    float* part = agg;   // agg (r) dead by the time k_x1 runs

    hipMemsetAsync(cnt, 0, ((size_t)N * 4 + 255) / 256 * 256 + (size_t)N * 4, stream); // covers cnt+fill

    int nf4 = N * DD / 4;
    int countBlocks = (E + 255) / 256;
    int prepBlocks = (nf4 + 128 * 256 / 4 + 255) / 256;
    // fused: count + bf16 prep + fold (independent block ranges)
    k_countprep<<<countBlocks + prepBlocks + 1, 256, 0, stream>>>(
        dst, cnt, E, feature, Wa1, ba1, attW1, attb1, feat_bf, Wa1b, fold,
        nf4, countBlocks, prepBlocks);
    k_scan<<<1, 1024, 0, stream>>>(cnt, offs, N);
    k_fill<<<(E + 255) / 256, 256, 0, stream>>>(src, dst, offs, fill, csr, E);

    int segBlocks = (N + 3) / 4;
    int chunkBlocks = N / 32;   // 625, exact
    // mean(feature_bf) -> agg
    k_seg_mean_bf<<<segBlocks, 256, 0, stream>>>(feat_bf, offs, csr, agg, N);
    // embed3 = normalize(agg @ Wf + bf) (f32 out + bf16 copy)
    k_gemm128<0><<<chunkBlocks, 256, 0, stream>>>(agg, Wf, bf, embed3_o, e3_bf, nullptr, nullptr, nullptr, N);
    // mean(embed3_bf) -> agg
    k_seg_mean_bf<<<segBlocks, 256, 0, stream>>>(e3_bf, offs, csr, agg, N);
    // z1 (bf16) = agg @ We1 + be1 ; a_src/a_dst
    k_gemm128<1><<<chunkBlocks, 256, 0, stream>>>(agg, We1, be1, nullptr, z1b, fold, a_src, a_dst, N);
    // attention -> r (reuse agg)
    k_att<<<segBlocks, 256, 0, stream>>>(z1b, offs, csr, a_src, a_dst, fold, agg, N);
    // s1 = softmax(r @ Wa1 + ba1)
    k_s1<<<chunkBlocks, 256, 0, stream>>>(agg, Wa1b, ba1, s1_o, N);
    // x1 = s1^T @ z1 (partials)
    k_x1<<<2 * X1_SPLIT, 512, 0, stream>>>(s1_o, z1b, part, N);
    // x1 reduce + lin2 fused
    k_lin2x<<<CC1 / 2, 256, 0, stream>>>(part, We2, be2, x1_o, lin2);
    // coarse outputs
    k_coarse<<<1, 128, 0, stream>>>(lin2, Wa2, ba2, s2_o, assign1_o, x2_o, embed0_o);
}

// Round 10
// 339.265 us; speedup vs baseline: 1.1659x; 1.0177x over previous
//
#include <hip/hip_runtime.h>
#include <hip/hip_bf16.h>
#include <math.h>

#define NN 20000
#define DD 128
#define CC1 256
#define CC2 32
#define X1_SPLIT 128

__device__ __forceinline__ unsigned short f2bf(float f) {
    unsigned int b = __float_as_uint(f);
    b = (b + 0x7fffu + ((b >> 16) & 1u)) >> 16;
    return (unsigned short)b;
}
__device__ __forceinline__ unsigned int f2bf2(float lo, float hi) {
    return (unsigned int)f2bf(lo) | ((unsigned int)f2bf(hi) << 16);
}
__device__ __forceinline__ float bfu(unsigned short u) { return __uint_as_float((unsigned int)u << 16); }
__device__ __forceinline__ float bf_lo(unsigned int u) { return __uint_as_float(u << 16); }
__device__ __forceinline__ float bf_hi(unsigned int u) { return __uint_as_float(u & 0xffff0000u); }

// ---------------- fused: edge count + bf16 prep + attW1 fold (block-range split) ----------------
__global__ __launch_bounds__(256) void k_countprep(const int* __restrict__ dst,
                                                   int* __restrict__ cnt, int E,
                                                   const float* __restrict__ feature,
                                                   const float* __restrict__ Wa1,
                                                   const float* __restrict__ ba1,
                                                   const float* __restrict__ attW1,
                                                   const float* __restrict__ attb1,
                                                   unsigned short* __restrict__ feat_bf,
                                                   unsigned short* __restrict__ Wa1b,
                                                   float* __restrict__ fold,
                                                   int nf4, int countBlocks, int prepBlocks) {
    int b = blockIdx.x;
    int t = threadIdx.x;
    if (b < countBlocks) {
        int e = b * 256 + t;
        if (e < E) atomicAdd(&cnt[dst[e]], 1);
        return;
    }
    b -= countBlocks;
    if (b < prepBlocks) {
        int i = b * 256 + t;
        int tot = nf4 + 128 * 256 / 4;
        if (i >= tot) return;
        float4 v;
        if (i < nf4) v = ((const float4*)feature)[i];
        else         v = ((const float4*)Wa1)[i - nf4];
        ushort4 u;
        u.x = f2bf(v.x); u.y = f2bf(v.y); u.z = f2bf(v.z); u.w = f2bf(v.w);
        if (i < nf4) ((ushort4*)feat_bf)[i] = u;
        else         ((ushort4*)Wa1b)[i - nf4] = u;
        return;
    }
    // fold block
    if (t < 128) {
        float vs = 0.f, vd = 0.f;
        for (int k = 0; k < CC1; k++) {
            float w = Wa1[t * CC1 + k];
            vs += w * attW1[k];
            vd += w * attW1[CC1 + k];
        }
        fold[t] = vs;
        fold[128 + t] = vd;
        if (t == 0) {
            float c = attb1[0];
            for (int k = 0; k < CC1; k++) c += ba1[k] * (attW1[k] + attW1[CC1 + k]);
            fold[256] = c;
        }
    }
}

__global__ void k_scan(const int* __restrict__ cnt, int* __restrict__ offs, int n) {
    __shared__ int part[1024];
    int t = threadIdx.x;
    int chunk = (n + 1023) / 1024;
    int lo = t * chunk, hi = min(lo + chunk, n);
    int s = 0;
    for (int i = lo; i < hi; i++) s += cnt[i];
    part[t] = s;
    __syncthreads();
    for (int d = 1; d < 1024; d <<= 1) {
        int v = (t >= d) ? part[t - d] : 0;
        __syncthreads();
        part[t] += v;
        __syncthreads();
    }
    int base = (t > 0) ? part[t - 1] : 0;
    for (int i = lo; i < hi; i++) { offs[i] = base; base += cnt[i]; }
    if (t == 1023) offs[n] = part[1023];
}

__global__ void k_fill(const int* __restrict__ src, const int* __restrict__ dst,
                       const int* __restrict__ offs, int* __restrict__ fill,
                       int* __restrict__ csr_src, int E) {
    int e = blockIdx.x * blockDim.x + threadIdx.x;
    if (e < E) {
        int d = dst[e];
        int pos = atomicAdd(&fill[d], 1);
        csr_src[offs[d] + pos] = src[e];
    }
}

// ---------------- per-dst mean over bf16 rows: quarter-wave per edge, 16 loads in flight ----------------
__global__ __launch_bounds__(256) void k_seg_mean_bf(const unsigned short* __restrict__ in,
                                                     const int* __restrict__ offs,
                                                     const int* __restrict__ csr_src,
                                                     float* __restrict__ out, int n) {
    int wave = (blockIdx.x * blockDim.x + threadIdx.x) >> 6;
    int lane = threadIdx.x & 63;
    if (wave >= n) return;
    int lo = offs[wave], hi = offs[wave + 1];
    int q = lane >> 4, l16 = lane & 15;
    const uint4* f = (const uint4*)in;   // 16 B = 8 bf16; row stride = 16 units
    float acc[8];
    #pragma unroll
    for (int j = 0; j < 8; j++) acc[j] = 0.f;
    int i = lo + q;
    while (i + 12 < hi) {
        int sa = csr_src[i], sb = csr_src[i + 4], sc = csr_src[i + 8], sd = csr_src[i + 12];
        uint4 va = f[(size_t)sa * 16 + l16];
        uint4 vb = f[(size_t)sb * 16 + l16];
        uint4 vc = f[(size_t)sc * 16 + l16];
        uint4 vd = f[(size_t)sd * 16 + l16];
        acc[0] += bf_lo(va.x) + bf_lo(vb.x) + bf_lo(vc.x) + bf_lo(vd.x);
        acc[1] += bf_hi(va.x) + bf_hi(vb.x) + bf_hi(vc.x) + bf_hi(vd.x);
        acc[2] += bf_lo(va.y) + bf_lo(vb.y) + bf_lo(vc.y) + bf_lo(vd.y);
        acc[3] += bf_hi(va.y) + bf_hi(vb.y) + bf_hi(vc.y) + bf_hi(vd.y);
        acc[4] += bf_lo(va.z) + bf_lo(vb.z) + bf_lo(vc.z) + bf_lo(vd.z);
        acc[5] += bf_hi(va.z) + bf_hi(vb.z) + bf_hi(vc.z) + bf_hi(vd.z);
        acc[6] += bf_lo(va.w) + bf_lo(vb.w) + bf_lo(vc.w) + bf_lo(vd.w);
        acc[7] += bf_hi(va.w) + bf_hi(vb.w) + bf_hi(vc.w) + bf_hi(vd.w);
        i += 16;
    }
    while (i < hi) {
        uint4 v = f[(size_t)csr_src[i] * 16 + l16];
        acc[0] += bf_lo(v.x); acc[1] += bf_hi(v.x);
        acc[2] += bf_lo(v.y); acc[3] += bf_hi(v.y);
        acc[4] += bf_lo(v.z); acc[5] += bf_hi(v.z);
        acc[6] += bf_lo(v.w); acc[7] += bf_hi(v.w);
        i += 4;
    }
    #pragma unroll
    for (int j = 0; j < 8; j++) {
        acc[j] += __shfl_xor(acc[j], 16);
        acc[j] += __shfl_xor(acc[j], 32);
    }
    if (q == 0) {
        float inv = 1.0f / (float)max(hi - lo, 1);
        *(float4*)&out[(size_t)wave * 128 + l16 * 8]     = make_float4(acc[0] * inv, acc[1] * inv, acc[2] * inv, acc[3] * inv);
        *(float4*)&out[(size_t)wave * 128 + l16 * 8 + 4] = make_float4(acc[4] * inv, acc[5] * inv, acc[6] * inv, acc[7] * inv);
    }
}

// ---------------- row GEMM [n,128]x[128,128]: one 32-row chunk/block, swizzled sT ----------------
// MODE 0: L2-normalize rows -> out f32 + out_bf
// MODE 1: out_bf only (z1 bf16); a_src/a_dst via folded attention vectors
template <int MODE>
__global__ __launch_bounds__(256) void k_gemm128(const float* __restrict__ in,
                                                 const float* __restrict__ W,
                                                 const float* __restrict__ b,
                                                 float* __restrict__ out,
                                                 unsigned short* __restrict__ out_bf,
                                                 const float* __restrict__ fold,
                                                 float* __restrict__ a_src,
                                                 float* __restrict__ a_dst, int n) {
    __shared__ float sW[128 * 128];   // 64 KB
    __shared__ float sT[128 * 32];    // 16 KB, swizzled transposed activations
    int t = threadIdx.x;
    for (int i = t; i < 4096; i += 256) ((float4*)sW)[i] = ((const float4*)W)[i];
    int r0 = blockIdx.x * 32;
    {
        int lrow = t >> 3, seg = t & 7;
        const float4* g = (const float4*)&in[(size_t)(r0 + lrow) * 128 + seg * 16];
        float4 v0 = g[0], v1 = g[1], v2 = g[2], v3 = g[3];
        int base = (((lrow >> 2) ^ seg) << 2) + (lrow & 3);
        int k0 = seg * 16;
        sT[(k0 + 0) * 32 + base] = v0.x; sT[(k0 + 1) * 32 + base] = v0.y;
        sT[(k0 + 2) * 32 + base] = v0.z; sT[(k0 + 3) * 32 + base] = v0.w;
        sT[(k0 + 4) * 32 + base] = v1.x; sT[(k0 + 5) * 32 + base] = v1.y;
        sT[(k0 + 6) * 32 + base] = v1.z; sT[(k0 + 7) * 32 + base] = v1.w;
        sT[(k0 + 8) * 32 + base] = v2.x; sT[(k0 + 9) * 32 + base] = v2.y;
        sT[(k0 + 10) * 32 + base] = v2.z; sT[(k0 + 11) * 32 + base] = v2.w;
        sT[(k0 + 12) * 32 + base] = v3.x; sT[(k0 + 13) * 32 + base] = v3.y;
        sT[(k0 + 14) * 32 + base] = v3.z; sT[(k0 + 15) * 32 + base] = v3.w;
    }
    int lane = t & 63;
    int wv = t >> 6;
    int j4 = (lane & 31) * 4;
    int rg = wv * 2 + (lane >> 5);    // 0..7 -> rows rg*4..rg*4+3
    float bj0 = b[j4], bj1 = b[j4 + 1], bj2 = b[j4 + 2], bj3 = b[j4 + 3];
    float vs0 = 0.f, vs1 = 0.f, vs2 = 0.f, vs3 = 0.f;
    float vd0 = 0.f, vd1 = 0.f, vd2 = 0.f, vd3 = 0.f;
    if (MODE == 1) {
        vs0 = fold[j4]; vs1 = fold[j4 + 1]; vs2 = fold[j4 + 2]; vs3 = fold[j4 + 3];
        vd0 = fold[128 + j4]; vd1 = fold[128 + j4 + 1]; vd2 = fold[128 + j4 + 2]; vd3 = fold[128 + j4 + 3];
    }
    __syncthreads();
    float acc[4][4];
    #pragma unroll
    for (int p = 0; p < 4; p++) { acc[p][0] = bj0; acc[p][1] = bj1; acc[p][2] = bj2; acc[p][3] = bj3; }
    for (int k = 0; k < 128; k++) {
        float4 w4 = *(const float4*)&sW[k * 128 + j4];
        float4 rv = *(const float4*)&sT[k * 32 + ((rg ^ (k >> 4)) << 2)];
        acc[0][0] += rv.x * w4.x; acc[0][1] += rv.x * w4.y; acc[0][2] += rv.x * w4.z; acc[0][3] += rv.x * w4.w;
        acc[1][0] += rv.y * w4.x; acc[1][1] += rv.y * w4.y; acc[1][2] += rv.y * w4.z; acc[1][3] += rv.y * w4.w;
        acc[2][0] += rv.z * w4.x; acc[2][1] += rv.z * w4.y; acc[2][2] += rv.z * w4.z; acc[2][3] += rv.z * w4.w;
        acc[3][0] += rv.w * w4.x; acc[3][1] += rv.w * w4.y; acc[3][2] += rv.w * w4.z; acc[3][3] += rv.w * w4.w;
    }
    #pragma unroll
    for (int p = 0; p < 4; p++) {
        int row = r0 + rg * 4 + p;
        if (MODE == 0) {
            float ss_ = acc[p][0] * acc[p][0] + acc[p][1] * acc[p][1] +
                        acc[p][2] * acc[p][2] + acc[p][3] * acc[p][3];
            ss_ += __shfl_xor(ss_, 16); ss_ += __shfl_xor(ss_, 8);
            ss_ += __shfl_xor(ss_, 4);  ss_ += __shfl_xor(ss_, 2); ss_ += __shfl_xor(ss_, 1);
            float scale = 1.0f / fmaxf(sqrtf(ss_), 1e-12f);
            float o0 = acc[p][0] * scale, o1 = acc[p][1] * scale, o2 = acc[p][2] * scale, o3 = acc[p][3] * scale;
            *(float4*)&out[(size_t)row * 128 + j4] = make_float4(o0, o1, o2, o3);
            ushort4 u; u.x = f2bf(o0); u.y = f2bf(o1); u.z = f2bf(o2); u.w = f2bf(o3);
            ((ushort4*)out_bf)[(size_t)row * 32 + (j4 >> 2)] = u;
        } else {
            ushort4 u; u.x = f2bf(acc[p][0]); u.y = f2bf(acc[p][1]); u.z = f2bf(acc[p][2]); u.w = f2bf(acc[p][3]);
            ((ushort4*)out_bf)[(size_t)row * 32 + (j4 >> 2)] = u;
            float ps = acc[p][0] * vs0 + acc[p][1] * vs1 + acc[p][2] * vs2 + acc[p][3] * vs3;
            float pd = acc[p][0] * vd0 + acc[p][1] * vd1 + acc[p][2] * vd2 + acc[p][3] * vd3;
            ps += __shfl_xor(ps, 16); ps += __shfl_xor(ps, 8); ps += __shfl_xor(ps, 4);
            ps += __shfl_xor(ps, 2);  ps += __shfl_xor(ps, 1);
            pd += __shfl_xor(pd, 16); pd += __shfl_xor(pd, 8); pd += __shfl_xor(pd, 4);
            pd += __shfl_xor(pd, 2);  pd += __shfl_xor(pd, 1);
            if ((lane & 31) == 0) { a_src[row] = ps; a_dst[row] = pd; }
        }
    }
}

// ---------------- sparse GAT: quarter-wave per edge, 16 loads in flight, bf16 r output ----------------
__global__ __launch_bounds__(256) void k_att(const unsigned short* __restrict__ z1b,
                                             const int* __restrict__ offs,
                                             const int* __restrict__ csr_src,
                                             const float* __restrict__ a_src,
                                             const float* __restrict__ a_dst,
                                             const float* __restrict__ fold,
                                             unsigned short* __restrict__ r_bf, int n) {
    int wave = (blockIdx.x * blockDim.x + threadIdx.x) >> 6;
    int lane = threadIdx.x & 63;
    if (wave >= n) return;
    int lo = offs[wave], hi = offs[wave + 1];
    float C0 = fold[256] + a_dst[wave];
    int q = lane >> 4, l16 = lane & 15;
    const uint4* z4 = (const uint4*)z1b;  // 16 B = 8 bf16
    float acc[8];
    #pragma unroll
    for (int j = 0; j < 8; j++) acc[j] = 0.f;
    float den = 0.f;
    int i = lo + q;
    while (i + 12 < hi) {
        int sa = csr_src[i], sb = csr_src[i + 4], sc = csr_src[i + 8], sd = csr_src[i + 12];
        float aa = a_src[sa], ab = a_src[sb], ac = a_src[sc], ad = a_src[sd];
        uint4 va = z4[(size_t)sa * 16 + l16];
        uint4 vb = z4[(size_t)sb * 16 + l16];
        uint4 vc = z4[(size_t)sc * 16 + l16];
        uint4 vd = z4[(size_t)sd * 16 + l16];
        float ea = aa + C0; ea = ea > 0.f ? ea : 0.01f * ea;
        float eb = ab + C0; eb = eb > 0.f ? eb : 0.01f * eb;
        float ec = ac + C0; ec = ec > 0.f ? ec : 0.01f * ec;
        float ed = ad + C0; ed = ed > 0.f ? ed : 0.01f * ed;
        float la = __expf(fminf(ea, 60.f)), lb = __expf(fminf(eb, 60.f));
        float lc = __expf(fminf(ec, 60.f)), ld = __expf(fminf(ed, 60.f));
        den += (la + lb) + (lc + ld);
        acc[0] += la * bf_lo(va.x) + lb * bf_lo(vb.x) + lc * bf_lo(vc.x) + ld * bf_lo(vd.x);
        acc[1] += la * bf_hi(va.x) + lb * bf_hi(vb.x) + lc * bf_hi(vc.x) + ld * bf_hi(vd.x);
        acc[2] += la * bf_lo(va.y) + lb * bf_lo(vb.y) + lc * bf_lo(vc.y) + ld * bf_lo(vd.y);
        acc[3] += la * bf_hi(va.y) + lb * bf_hi(vb.y) + lc * bf_hi(vc.y) + ld * bf_hi(vd.y);
        acc[4] += la * bf_lo(va.z) + lb * bf_lo(vb.z) + lc * bf_lo(vc.z) + ld * bf_lo(vd.z);
        acc[5] += la * bf_hi(va.z) + lb * bf_hi(vb.z) + lc * bf_hi(vc.z) + ld * bf_hi(vd.z);
        acc[6] += la * bf_lo(va.w) + lb * bf_lo(vb.w) + lc * bf_lo(vc.w) + ld * bf_lo(vd.w);
        acc[7] += la * bf_hi(va.w) + lb * bf_hi(vb.w) + lc * bf_hi(vc.w) + ld * bf_hi(vd.w);
        i += 16;
    }
    while (i < hi) {
        int s = csr_src[i];
        float a = a_src[s];
        uint4 v = z4[(size_t)s * 16 + l16];
        float e = a + C0; e = e > 0.f ? e : 0.01f * e;
        float al = __expf(fminf(e, 60.f));
        den += al;
        acc[0] += al * bf_lo(v.x); acc[1] += al * bf_hi(v.x);
        acc[2] += al * bf_lo(v.y); acc[3] += al * bf_hi(v.y);
        acc[4] += al * bf_lo(v.z); acc[5] += al * bf_hi(v.z);
        acc[6] += al * bf_lo(v.w); acc[7] += al * bf_hi(v.w);
        i += 4;
    }
    den += __shfl_xor(den, 16);
    den += __shfl_xor(den, 32);
    #pragma unroll
    for (int j = 0; j < 8; j++) {
        acc[j] += __shfl_xor(acc[j], 16);
        acc[j] += __shfl_xor(acc[j], 32);
    }
    if (q == 0) {
        float invden = 1.0f / den;
        uint4 u;
        u.x = f2bf2(acc[0] * invden, acc[1] * invden);
        u.y = f2bf2(acc[2] * invden, acc[3] * invden);
        u.z = f2bf2(acc[4] * invden, acc[5] * invden);
        u.w = f2bf2(acc[6] * invden, acc[7] * invden);
        ((uint4*)r_bf)[(size_t)wave * 16 + l16] = u;
    }
}

// ---------------- s1 = softmax(r @ Wa1 + ba1): bf16 r input, bf16 W copy, swizzled sT ----------------
__global__ __launch_bounds__(256) void k_s1(const unsigned short* __restrict__ r_bf,
                                            const unsigned short* __restrict__ Wa1b,
                                            const float* __restrict__ ba1,
                                            float* __restrict__ s1, int n) {
    __shared__ unsigned short sW2[128 * 256];  // 64 KB bf16 (raw copy, no cvt)
    __shared__ float sT[128 * 32];             // 16 KB swizzled
    int t = threadIdx.x;
    {
        // 128*256 ushorts = 4096 uint4; 256 threads x 16 iterations
        const uint4* g = (const uint4*)Wa1b;
        uint4* d = (uint4*)sW2;
        #pragma unroll
        for (int i = 0; i < 16; i++) d[t + i * 256] = g[t + i * 256];
    }
    int r0 = blockIdx.x * 32;
    {
        int lrow = t >> 3, seg = t & 7;
        const uint4* g = (const uint4*)r_bf;   // row stride = 16 units of 8 bf16
        uint4 v0 = g[(size_t)(r0 + lrow) * 16 + seg * 2];
        uint4 v1 = g[(size_t)(r0 + lrow) * 16 + seg * 2 + 1];
        int base = (((lrow >> 2) ^ seg) << 2) + (lrow & 3);
        int k0 = seg * 16;
        sT[(k0 + 0) * 32 + base] = bf_lo(v0.x); sT[(k0 + 1) * 32 + base] = bf_hi(v0.x);
        sT[(k0 + 2) * 32 + base] = bf_lo(v0.y); sT[(k0 + 3) * 32 + base] = bf_hi(v0.y);
        sT[(k0 + 4) * 32 + base] = bf_lo(v0.z); sT[(k0 + 5) * 32 + base] = bf_hi(v0.z);
        sT[(k0 + 6) * 32 + base] = bf_lo(v0.w); sT[(k0 + 7) * 32 + base] = bf_hi(v0.w);
        sT[(k0 + 8) * 32 + base] = bf_lo(v1.x); sT[(k0 + 9) * 32 + base] = bf_hi(v1.x);
        sT[(k0 + 10) * 32 + base] = bf_lo(v1.y); sT[(k0 + 11) * 32 + base] = bf_hi(v1.y);
        sT[(k0 + 12) * 32 + base] = bf_lo(v1.z); sT[(k0 + 13) * 32 + base] = bf_hi(v1.z);
        sT[(k0 + 14) * 32 + base] = bf_lo(v1.w); sT[(k0 + 15) * 32 + base] = bf_hi(v1.w);
    }
    int cg = t & 31, rg = t >> 5;
    int j8 = cg * 8;
    float bj[8];
    #pragma unroll
    for (int q = 0; q < 8; q++) bj[q] = ba1[j8 + q];
    __syncthreads();
    float acc[4][8];
    #pragma unroll
    for (int p = 0; p < 4; p++)
        #pragma unroll
        for (int q = 0; q < 8; q++) acc[p][q] = bj[q];
    for (int k = 0; k < 128; k++) {
        uint4 wz = *(const uint4*)&sW2[k * 256 + j8];
        float w0 = bf_lo(wz.x), w1 = bf_hi(wz.x), w2 = bf_lo(wz.y), w3 = bf_hi(wz.y);
        float w4 = bf_lo(wz.z), w5 = bf_hi(wz.z), w6 = bf_lo(wz.w), w7 = bf_hi(wz.w);
        float4 rv = *(const float4*)&sT[k * 32 + ((rg ^ (k >> 4)) << 2)];
        acc[0][0] += rv.x * w0; acc[0][1] += rv.x * w1; acc[0][2] += rv.x * w2; acc[0][3] += rv.x * w3;
        acc[0][4] += rv.x * w4; acc[0][5] += rv.x * w5; acc[0][6] += rv.x * w6; acc[0][7] += rv.x * w7;
        acc[1][0] += rv.y * w0; acc[1][1] += rv.y * w1; acc[1][2] += rv.y * w2; acc[1][3] += rv.y * w3;
        acc[1][4] += rv.y * w4; acc[1][5] += rv.y * w5; acc[1][6] += rv.y * w6; acc[1][7] += rv.y * w7;
        acc[2][0] += rv.z * w0; acc[2][1] += rv.z * w1; acc[2][2] += rv.z * w2; acc[2][3] += rv.z * w3;
        acc[2][4] += rv.z * w4; acc[2][5] += rv.z * w5; acc[2][6] += rv.z * w6; acc[2][7] += rv.z * w7;
        acc[3][0] += rv.w * w0; acc[3][1] += rv.w * w1; acc[3][2] += rv.w * w2; acc[3][3] += rv.w * w3;
        acc[3][4] += rv.w * w4; acc[3][5] += rv.w * w5; acc[3][6] += rv.w * w6; acc[3][7] += rv.w * w7;
    }
    #pragma unroll
    for (int p = 0; p < 4; p++) {
        int row = r0 + rg * 4 + p;
        float mx = acc[p][0];
        #pragma unroll
        for (int q = 1; q < 8; q++) mx = fmaxf(mx, acc[p][q]);
        mx = fmaxf(mx, __shfl_xor(mx, 16)); mx = fmaxf(mx, __shfl_xor(mx, 8));
        mx = fmaxf(mx, __shfl_xor(mx, 4));  mx = fmaxf(mx, __shfl_xor(mx, 2));
        mx = fmaxf(mx, __shfl_xor(mx, 1));
        float e[8], sm = 0.f;
        #pragma unroll
        for (int q = 0; q < 8; q++) { e[q] = __expf(acc[p][q] - mx); sm += e[q]; }
        sm += __shfl_xor(sm, 16); sm += __shfl_xor(sm, 8); sm += __shfl_xor(sm, 4);
        sm += __shfl_xor(sm, 2);  sm += __shfl_xor(sm, 1);
        float inv = 1.0f / sm;
        *(float4*)&s1[(size_t)row * 256 + j8]     = make_float4(e[0] * inv, e[1] * inv, e[2] * inv, e[3] * inv);
        *(float4*)&s1[(size_t)row * 256 + j8 + 4] = make_float4(e[4] * inv, e[5] * inv, e[6] * inv, e[7] * inv);
    }
}

// ---------------- x1 = s1^T @ z1: 256 blocks (128 row-splits x 2 col-halves), bf16 z ----------------
__global__ __launch_bounds__(512) void k_x1(const float* __restrict__ s1,
                                            const unsigned short* __restrict__ z1b,
                                            float* __restrict__ part, int n) {
    __shared__ float ss[16][128];            // 8 KB
    __shared__ unsigned short sz[16][128];   // 4 KB
    int t = threadIdx.x;
    int rs = blockIdx.x >> 1;
    int ch = blockIdx.x & 1;
    int c4 = (t & 31) * 4;
    int dg = t >> 5;
    int d0 = dg * 8;
    float a[4][8];
    #pragma unroll
    for (int c = 0; c < 4; c++)
        #pragma unroll
        for (int d = 0; d < 8; d++) a[c][d] = 0.f;
    int rows_per_block = (n + X1_SPLIT - 1) / X1_SPLIT;
    int row0 = rs * rows_per_block;
    int row_end = min(row0 + rows_per_block, n);
    int srow = t >> 5, scol4 = (t & 31) * 4;
    for (int r = row0; r < row_end; r += 16) {
        int nb = min(16, row_end - r);
        __syncthreads();
        if (srow < nb) {
            *(float4*)&ss[srow][scol4] = *(const float4*)&s1[(size_t)(r + srow) * 256 + ch * 128 + scol4];
            ((ushort4*)&sz[srow][0])[t & 31] = ((const ushort4*)z1b)[(size_t)(r + srow) * 32 + (t & 31)];
        }
        __syncthreads();
        for (int i = 0; i < nb; i++) {
            float4 sv = *(const float4*)&ss[i][c4];
            uint4 zz = *(const uint4*)&sz[i][d0];
            float zf[8];
            zf[0] = bf_lo(zz.x); zf[1] = bf_hi(zz.x); zf[2] = bf_lo(zz.y); zf[3] = bf_hi(zz.y);
            zf[4] = bf_lo(zz.z); zf[5] = bf_hi(zz.z); zf[6] = bf_lo(zz.w); zf[7] = bf_hi(zz.w);
            #pragma unroll
            for (int d = 0; d < 8; d++) {
                a[0][d] += sv.x * zf[d];
                a[1][d] += sv.y * zf[d];
                a[2][d] += sv.z * zf[d];
                a[3][d] += sv.w * zf[d];
            }
        }
    }
    size_t base = (size_t)rs * 32768 + (size_t)(ch * 128 + c4) * 128 + d0;
    #pragma unroll
    for (int c = 0; c < 4; c++) {
        *(float4*)&part[base + (size_t)c * 128]     = make_float4(a[c][0], a[c][1], a[c][2], a[c][3]);
        *(float4*)&part[base + (size_t)c * 128 + 4] = make_float4(a[c][4], a[c][5], a[c][6], a[c][7]);
    }
}

// ---------------- fused: x1 = reduce(part); lin2 = x1 @ We2 + be2 ----------------
__global__ __launch_bounds__(256) void k_lin2x(const float* __restrict__ part,
                                               const float* __restrict__ We2,
                                               const float* __restrict__ be2,
                                               float* __restrict__ x1,
                                               float* __restrict__ lin2) {
    int half = threadIdx.x >> 7, j = threadIdx.x & 127;
    int row = blockIdx.x * 2 + half;
    __shared__ float sr[2][128];
    float s = 0.f;
    const float* p = part + (size_t)row * 128 + j;
    #pragma unroll 8
    for (int q = 0; q < X1_SPLIT; q++) s += p[(size_t)q * 32768];
    x1[row * 128 + j] = s;
    sr[half][j] = s;
    __syncthreads();
    float acc = be2[j];
    #pragma unroll 8
    for (int k = 0; k < 128; k++) acc += sr[half][k] * We2[k * 128 + j];
    lin2[row * 128 + j] = acc;
}

// ---------------- coarse level ----------------
__global__ void k_coarse(const float* __restrict__ lin2, const float* __restrict__ Wa2,
                         const float* __restrict__ ba2,
                         float* __restrict__ s2, float* __restrict__ assign1,
                         float* __restrict__ x2, float* __restrict__ embed0) {
    __shared__ float mrow[128];
    __shared__ float p[32];
    __shared__ float red[2];
    int t = threadIdx.x; // 128 threads
    float s = 0.f;
    for (int i = 0; i < 256; i++) s += lin2[i * 128 + t];
    mrow[t] = s / 256.0f;
    __syncthreads();
    if (t < 32) {
        float z = ba2[t];
        for (int d = 0; d < 128; d++) z += mrow[d] * Wa2[d * 32 + t];
        float mx = z;
        for (int o = 16; o > 0; o >>= 1) mx = fmaxf(mx, __shfl_xor(mx, o, 32));
        float ex = __expf(z - mx);
        float sm = ex;
        for (int o = 16; o > 0; o >>= 1) sm += __shfl_xor(sm, o, 32);
        p[t] = ex / sm;
        assign1[t] = 1.0f;
    }
    __syncthreads();
    for (int i = t; i < 256 * 32; i += 128) s2[i] = p[i & 31];
    for (int i = t; i < 32 * 128; i += 128) {
        int k = i >> 7, d = i & 127;
        x2[i] = 256.0f * p[k] * mrow[d];
    }
    float tot = 0.f;
    for (int i = t; i < 32 * 128; i += 128) {
        int k = i >> 7, d = i & 127;
        tot += 256.0f * p[k] * mrow[d];
    }
    for (int o = 32; o > 0; o >>= 1) tot += __shfl_xor(tot, o);
    if ((t & 63) == 0) red[t >> 6] = tot;
    __syncthreads();
    if (t == 0) embed0[0] = (red[0] + red[1]) / 4096.0f;
}

extern "C" void kernel_launch(void* const* d_in, const int* in_sizes, int n_in,
                              void* d_out, int out_size, void* d_ws, size_t ws_size,
                              hipStream_t stream) {
    const float* feature = (const float*)d_in[0];
    const int*   eidx    = (const int*)d_in[1];
    const float* Wf   = (const float*)d_in[2];
    const float* bf   = (const float*)d_in[3];
    const float* We1  = (const float*)d_in[4];
    const float* be1  = (const float*)d_in[5];
    const float* Wa1  = (const float*)d_in[6];
    const float* ba1  = (const float*)d_in[7];
    const float* attW1= (const float*)d_in[8];
    const float* attb1= (const float*)d_in[9];
    const float* We2  = (const float*)d_in[10];
    const float* be2  = (const float*)d_in[11];
    const float* Wa2  = (const float*)d_in[12];
    const float* ba2  = (const float*)d_in[13];

    const int N = in_sizes[0] / DD;     // 20000
    const int E = in_sizes[1] / 2;      // 340000
    const int* src = eidx;
    const int* dst = eidx + E;

    // d_out layout
    float* out = (float*)d_out;
    float* s1_o      = out;
    float* s2_o      = s1_o + (size_t)N * CC1;
    float* assign1_o = s2_o + CC1 * CC2;
    float* embed3_o  = assign1_o + CC2;
    float* x1_o      = embed3_o + (size_t)N * DD;
    float* x2_o      = x1_o + CC1 * DD;
    float* embed0_o  = x2_o + CC2 * DD;

    // workspace carve (cnt and fill adjacent -> one memset)
    char* w = (char*)d_ws;
    auto alloc = [&](size_t bytes) { void* p = (void*)w; w += ((bytes + 255) / 256) * 256; return p; };
    int* cnt   = (int*)alloc((size_t)N * 4);
    int* fill  = (int*)alloc((size_t)N * 4);
    int* offs  = (int*)alloc((size_t)(N + 1) * 4);
    int* csr   = (int*)alloc((size_t)E * 4);
    float* fold = (float*)alloc(257 * 4);
    unsigned short* feat_bf = (unsigned short*)alloc((size_t)N * DD * 2);
    unsigned short* e3_bf   = (unsigned short*)alloc((size_t)N * DD * 2);
    unsigned short* z1b     = (unsigned short*)alloc((size_t)N * DD * 2);
    unsigned short* r_bf    = (unsigned short*)alloc((size_t)N * DD * 2);
    unsigned short* Wa1b    = (unsigned short*)alloc((size_t)128 * 256 * 2);
    float* a_src = (float*)alloc((size_t)N * 4);
    float* a_dst = (float*)alloc((size_t)N * 4);
    float* lin2  = (float*)alloc((size_t)CC1 * DD * 4);
    size_t agg_bytes = (size_t)N * DD * 4;
    size_t part_bytes = (size_t)X1_SPLIT * CC1 * DD * 4;   // 16.78 MB
    float* agg  = (float*)alloc(agg_bytes > part_bytes ? agg_bytes : part_bytes);
    float* part = agg;   // agg dead by the time k_x1 runs

    hipMemsetAsync(cnt, 0, ((size_t)N * 4 + 255) / 256 * 256 + (size_t)N * 4, stream); // covers cnt+fill

    int nf4 = N * DD / 4;
    int countBlocks = (E + 255) / 256;
    int prepBlocks = (nf4 + 128 * 256 / 4 + 255) / 256;
    // fused: count + bf16 prep + fold (independent block ranges)
    k_countprep<<<countBlocks + prepBlocks + 1, 256, 0, stream>>>(
        dst, cnt, E, feature, Wa1, ba1, attW1, attb1, feat_bf, Wa1b, fold,
        nf4, countBlocks, prepBlocks);
    k_scan<<<1, 1024, 0, stream>>>(cnt, offs, N);
    k_fill<<<(E + 255) / 256, 256, 0, stream>>>(src, dst, offs, fill, csr, E);

    int segBlocks = (N + 3) / 4;
    int chunkBlocks = N / 32;   // 625, exact
    // mean(feature_bf) -> agg
    k_seg_mean_bf<<<segBlocks, 256, 0, stream>>>(feat_bf, offs, csr, agg, N);
    // embed3 = normalize(agg @ Wf + bf) (f32 out + bf16 copy)
    k_gemm128<0><<<chunkBlocks, 256, 0, stream>>>(agg, Wf, bf, embed3_o, e3_bf, nullptr, nullptr, nullptr, N);
    // mean(embed3_bf) -> agg
    k_seg_mean_bf<<<segBlocks, 256, 0, stream>>>(e3_bf, offs, csr, agg, N);
    // z1 (bf16) = agg @ We1 + be1 ; a_src/a_dst
    k_gemm128<1><<<chunkBlocks, 256, 0, stream>>>(agg, We1, be1, nullptr, z1b, fold, a_src, a_dst, N);
    // attention -> r (bf16)
    k_att<<<segBlocks, 256, 0, stream>>>(z1b, offs, csr, a_src, a_dst, fold, r_bf, N);
    // s1 = softmax(r @ Wa1 + ba1)
    k_s1<<<chunkBlocks, 256, 0, stream>>>(r_bf, Wa1b, ba1, s1_o, N);
    // x1 = s1^T @ z1 (partials)
    k_x1<<<2 * X1_SPLIT, 512, 0, stream>>>(s1_o, z1b, part, N);
    // x1 reduce + lin2 fused
    k_lin2x<<<CC1 / 2, 256, 0, stream>>>(part, We2, be2, x1_o, lin2);
    // coarse outputs
    k_coarse<<<1, 128, 0, stream>>>(lin2, Wa2, ba2, s2_o, assign1_o, x2_o, embed0_o);
}